// Round 18
// baseline (248.124 us; speedup 1.0000x reference)
//
#include <hip/hip_runtime.h>
#include <hip/hip_bf16.h>

typedef unsigned short u16;
typedef unsigned int u32;
typedef __attribute__((ext_vector_type(8))) short bf16x8;
typedef __attribute__((ext_vector_type(4))) float f32x4;

__device__ __forceinline__ u32 fbits(float f) { union { float f; u32 u; } a; a.f = f; return a.u; }
__device__ __forceinline__ u16 f2bf(float f) {   // RNE (prep only, cold)
    u32 u = fbits(f);
    return (u16)((u + 0x7FFFu + ((u >> 16) & 1u)) >> 16);
}
// hot-path round-half-up conversions
__device__ __forceinline__ u16 bfr(float f) { return (u16)((fbits(f) + 0x8000u) >> 16); }
__device__ __forceinline__ u32 pk2(float lo, float hi) {
    return __builtin_amdgcn_perm(fbits(hi) + 0x8000u, fbits(lo) + 0x8000u, 0x07060302u);
}
__device__ __forceinline__ float bf2f(u16 b) {
    union { u32 u; float f; } a; a.u = ((u32)b) << 16; return a.f;
}
// transcendental-free GELU: t*sigma(1.702t), odd quintic, clamp +-3.
__device__ __forceinline__ float gelu_poly(float t) {
    float u = fminf(3.0f, fmaxf(-3.0f, t));
    float u2 = u * u;
    float w = fmaf(u2, 0.00319581f, -0.0550159f);
    w = fmaf(u2, w, 0.401174f);
    float sg = fmaf(u, w, 0.5f);
    return t * sg;
}

#define MFMA(a, b, c) __builtin_amdgcn_mfma_f32_16x16x32_bf16(a, b, c, 0, 0, 0)

// async global->LDS, 16B per lane; dst must be wave-uniform (HW adds lane*16)
__device__ __forceinline__ void gload16(const u16* g, u16* l) {
    __builtin_amdgcn_global_load_lds(
        (const __attribute__((address_space(1))) void*)g,
        (__attribute__((address_space(3))) void*)l, 16, 0, 0);
}

// ---------- prep ----------
// wout: [0,49152) qkv row-major | [49152,81920) projws fragment-tile order
//       [81920,212992) wms: 16 chunks x (8 fc1 tiles + 8 fc2 tiles) x 512
// fc1 tiles use PERMUTED N and K order so mlp can pack LDS writes as b32:
//   N: hid = chunk*32 + 2*(lane&15) + n2   (lane owns adjacent hid pair)
//   K: position q in y-storage holds actual chan (q&1)*16 + (q>>1)
// fc2 K-order = storage position = actual hid offset (identity) -> unchanged.
// bias_lane pre-scaled by 1/ln2 (max-free exp2 softmax).
__global__ void swin_prep_kernel(const float* __restrict__ qkv_w, const float* __restrict__ proj_w,
                                 const float* __restrict__ fc1_w, const float* __restrict__ fc2_w,
                                 const float* __restrict__ rpb, u16* __restrict__ wout,
                                 float* __restrict__ bias_lane)
{
    int idx = blockIdx.x * 256 + threadIdx.x;
    if (idx < 49152) wout[idx] = f2bf(qkv_w[idx]);
    else if (idx < 81920) {
        int j = idx - 49152;
        int tile = j >> 9, lane = (j >> 3) & 63, e = j & 7;
        int nt = tile >> 2, ks = tile & 3;
        wout[idx] = f2bf(proj_w[(nt * 16 + (lane & 15)) * 128 + ks * 32 + (lane >> 4) * 8 + e]);
    } else if (idx < 212992) {
        int j = idx - 81920;
        int chunk = j >> 13, rest = j & 8191;
        int tile = rest >> 9, lane = (rest >> 3) & 63, e = rest & 7;
        float v;
        if (tile < 8) {
            int n2 = tile >> 2, ks = tile & 3;
            int kp = (lane >> 4) * 8 + e;   // position within 32-block
            v = fc1_w[(chunk * 32 + 2 * (lane & 15) + n2) * 128 +
                      ks * 32 + (kp & 1) * 16 + (kp >> 1)];
        } else {
            int nt = tile - 8;
            v = fc2_w[(nt * 16 + (lane & 15)) * 512 + chunk * 32 + (lane >> 4) * 8 + e];
        }
        wout[idx] = f2bf(v);
    } else {
        int t = idx - 212992;  // < 65536
        int r = t & 3, lane = (t >> 2) & 63, nt = (t >> 8) & 3, mt = (t >> 10) & 3;
        int h = (t >> 12) & 3, v = (t >> 14) & 3;
        int i = mt * 16 + ((lane >> 4) << 2) + r;
        int j = nt * 16 + (lane & 15);
        int ri = i >> 3, ci = i & 7, rj = j >> 3, cj = j & 7;
        int rpi = (ri - rj + 7) * 15 + (ci - cj + 7);
        float bv = rpb[rpi * 4 + h];
        int vh = v >> 1, vw = v & 1;
        int regi = (vh ? (ri < 4 ? 1 : 2) : 0) * 3 + (vw ? (ci < 4 ? 1 : 2) : 0);
        int regj = (vh ? (rj < 4 ? 1 : 2) : 0) * 3 + (vw ? (cj < 4 ? 1 : 2) : 0);
        if (regi != regj) bv -= 100.0f;
        bias_lane[t] = bv * 1.4426950408889634f;   // pre-scale by 1/ln2 for exp2
    }
}

// ---------- fused LN1 + qkv + windowed attention (r17 verbatim) ----------
__global__ __launch_bounds__(512, 4) void swin_attn_kernel(
    const float* __restrict__ x, const float* __restrict__ g1, const float* __restrict__ b1,
    const float* __restrict__ qkvb, const u16* __restrict__ qkvw,
    const float* __restrict__ bias_lane, u16* __restrict__ attn_out)
{
    __shared__ __align__(16) u16 ldsX[8448];     // xln[64][132] | vT swz | outl[64][132]
    __shared__ __align__(16) u16 ldsQK[17408];   // q|k, then P[4][64][68]
    __shared__ float sb[640];                    // g1 | b1 | qkv_b

    int tid = threadIdx.x;
    int wid = blockIdx.x;
    int bb_ = wid >> 10, wh = (wid >> 5) & 31, ww = wid & 31;

    for (int i = tid; i < 640; i += 512) {
        float v;
        if (i < 128) v = g1[i];
        else if (i < 256) v = b1[i - 128];
        else v = qkvb[i - 256];
        sb[i] = v;
    }

    // ---- phase 1: gather rolled x rows, LN1 -> xln ----
    int trow = tid >> 3, seg = tid & 7;
    int rn = trow >> 3, cn = trow & 7;
    int srow = (wh * 8 + rn + 4) & 255;
    int scol = (ww * 8 + cn + 4) & 255;
    long grow = (long)bb_ * 65536 + srow * 256 + scol;
    const float4* xrow = (const float4*)(x + grow * 128 + seg * 16);
    float4 xv[4];
    #pragma unroll
    for (int i = 0; i < 4; ++i) xv[i] = xrow[i];
    __syncthreads();  // sb visible

    float s1 = 0.0f, s2 = 0.0f;
    #pragma unroll
    for (int i = 0; i < 4; ++i) {
        float4 v = xv[i];
        s1 += v.x + v.y + v.z + v.w;
        s2 += v.x * v.x + v.y * v.y + v.z * v.z + v.w * v.w;
    }
    #pragma unroll
    for (int off = 1; off < 8; off <<= 1) { s1 += __shfl_xor(s1, off); s2 += __shfl_xor(s2, off); }
    float mu = s1 * 0.0078125f;
    float rstd = rsqrtf(s2 * 0.0078125f - mu * mu + 1e-5f);
    {
        u32 pk[8];
        #pragma unroll
        for (int i = 0; i < 4; ++i) {
            float vv[4] = {xv[i].x, xv[i].y, xv[i].z, xv[i].w};
            float y0, y1, y2, y3;
            {
                int c = seg * 16 + i * 4;
                y0 = (vv[0] - mu) * rstd * sb[c + 0] + sb[128 + c + 0];
                y1 = (vv[1] - mu) * rstd * sb[c + 1] + sb[128 + c + 1];
                y2 = (vv[2] - mu) * rstd * sb[c + 2] + sb[128 + c + 2];
                y3 = (vv[3] - mu) * rstd * sb[c + 3] + sb[128 + c + 3];
            }
            pk[i * 2]     = pk2(y0, y1);
            pk[i * 2 + 1] = pk2(y2, y3);
        }
        *(uint4*)&ldsX[trow * 132 + seg * 16] = *(uint4*)&pk[0];
        *(uint4*)&ldsX[trow * 132 + seg * 16 + 8] = *(uint4*)&pk[4];
    }
    __syncthreads();

    // ---- phase 2: qkv GEMM (M=64,N=384,K=128); wave w owns nt = 3w..3w+2 ----
    int wave = tid >> 6, lane = tid & 63, l15 = lane & 15, lg = lane >> 4;
    int mrow = lg * 4;
    bf16x8 afr[4][4];
    #pragma unroll
    for (int mt = 0; mt < 4; ++mt)
        #pragma unroll
        for (int ks = 0; ks < 4; ++ks)
            afr[mt][ks] = *(const bf16x8*)&ldsX[(mt * 16 + l15) * 132 + ks * 32 + lg * 8];
    __syncthreads();   // xln fully consumed; region becomes vT
    #pragma unroll 1
    for (int nn = 0; nn < 3; ++nn) {
        int nt = wave * 3 + nn;
        int n = nt * 16 + l15;
        const u16* wp = qkvw + n * 128 + lg * 8;
        bf16x8 bfr_[4];
        #pragma unroll
        for (int ks = 0; ks < 4; ++ks) bfr_[ks] = *(const bf16x8*)(wp + ks * 32);
        f32x4 acc[4];
        #pragma unroll
        for (int mt = 0; mt < 4; ++mt) acc[mt] = (f32x4){0.0f, 0.0f, 0.0f, 0.0f};
        #pragma unroll
        for (int ks = 0; ks < 4; ++ks)
            #pragma unroll
            for (int mt = 0; mt < 4; ++mt)
                acc[mt] = MFMA(afr[mt][ks], bfr_[ks], acc[mt]);
        float bias = sb[256 + n];
        if (n < 128) {
            #pragma unroll
            for (int mt = 0; mt < 4; ++mt)
                #pragma unroll
                for (int r = 0; r < 4; ++r)
                    ldsQK[(mt * 16 + mrow + r) * 132 + n] = bfr(acc[mt][r] + bias);
        } else if (n < 256) {
            #pragma unroll
            for (int mt = 0; mt < 4; ++mt)
                #pragma unroll
                for (int r = 0; r < 4; ++r)
                    ldsQK[8448 + (mt * 16 + mrow + r) * 132 + (n - 128)] = bfr(acc[mt][r] + bias);
        } else {
            int row = n - 256;                      // v dim index 0..127
            int sw = (row & 7) << 4;                // T2 XOR swizzle (16B granules)
            #pragma unroll
            for (int mt = 0; mt < 4; ++mt) {        // v^T: 4 consecutive tokens -> uint2
                uint2 pv;
                pv.x = pk2(acc[mt][0] + bias, acc[mt][1] + bias);
                pv.y = pk2(acc[mt][2] + bias, acc[mt][3] + bias);
                int cb = ((mt * 16 + mrow) * 2) ^ sw;
                *(uint2*)((char*)ldsX + row * 128 + cb) = pv;
            }
        }
    }
    __syncthreads();

    // ---- phase 3: attention; wave pair per head; max-free exp2 softmax ----
    int h = wave >> 1, half = wave & 1;
    int v4 = ((wh == 31) ? 2 : 0) | ((ww == 31) ? 1 : 0);
    const float4* blp = (const float4*)bias_lane;
    bf16x8 bk[4];
    #pragma unroll
    for (int nt = 0; nt < 4; ++nt)
        bk[nt] = *(const bf16x8*)&ldsQK[8448 + (nt * 16 + l15) * 132 + h * 32 + lg * 8];
    f32x4 sS[2][4];
    #pragma unroll
    for (int m2 = 0; m2 < 2; ++m2) {
        int mt = half * 2 + m2;
        bf16x8 aq = *(const bf16x8*)&ldsQK[(mt * 16 + l15) * 132 + h * 32 + lg * 8];
        #pragma unroll
        for (int nt = 0; nt < 4; ++nt) {
            f32x4 z = (f32x4){0.0f, 0.0f, 0.0f, 0.0f};
            z = MFMA(aq, bk[nt], z);
            float4 bl = blp[((v4 * 4 + h) * 16 + mt * 4 + nt) * 64 + lane];
            sS[m2][nt][0] = z[0] * 0.2550349f + bl.x;
            sS[m2][nt][1] = z[1] * 0.2550349f + bl.y;
            sS[m2][nt][2] = z[2] * 0.2550349f + bl.z;
            sS[m2][nt][3] = z[3] * 0.2550349f + bl.w;
        }
    }
    float rinv[2][4];
    #pragma unroll
    for (int m2 = 0; m2 < 2; ++m2) {
        #pragma unroll
        for (int r = 0; r < 4; ++r) {
            float sum = 0.0f;
            #pragma unroll
            for (int nt = 0; nt < 4; ++nt) {
                float p = exp2f(sS[m2][nt][r]);   // no max-shift needed (|S|<~3)
                sS[m2][nt][r] = p;
                sum += p;
            }
            #pragma unroll
            for (int off = 1; off < 16; off <<= 1) sum += __shfl_xor(sum, off);
            rinv[m2][r] = __builtin_amdgcn_rcpf(sum);
        }
    }
    __syncthreads();   // all q/k reads complete before P overlays the region
    #pragma unroll
    for (int m2 = 0; m2 < 2; ++m2) {
        int mt = half * 2 + m2;
        #pragma unroll
        for (int nt = 0; nt < 4; ++nt)
            #pragma unroll
            for (int r = 0; r < 4; ++r)
                ldsQK[h * 4352 + (mt * 16 + mrow + r) * 68 + nt * 16 + l15] = bfr(sS[m2][nt][r]);
    }
    __syncthreads();

    // PV: out = P @ V (V from swizzled region)
    f32x4 o[2][2];
    #pragma unroll
    for (int m2 = 0; m2 < 2; ++m2)
        #pragma unroll
        for (int np = 0; np < 2; ++np) o[m2][np] = (f32x4){0.0f, 0.0f, 0.0f, 0.0f};
    #pragma unroll
    for (int kt = 0; kt < 2; ++kt) {
        bf16x8 pa[2];
        #pragma unroll
        for (int m2 = 0; m2 < 2; ++m2) {
            int mt = half * 2 + m2;
            pa[m2] = *(const bf16x8*)&ldsQK[h * 4352 + (mt * 16 + l15) * 68 + kt * 32 + lg * 8];
        }
        #pragma unroll
        for (int np = 0; np < 2; ++np) {
            int vr = h * 32 + np * 16 + l15;
            int cb = (kt * 64 + lg * 16) ^ ((vr & 7) << 4);
            bf16x8 bv = *(const bf16x8*)((const char*)ldsX + vr * 128 + cb);
            #pragma unroll
            for (int m2 = 0; m2 < 2; ++m2)
                o[m2][np] = MFMA(pa[m2], bv, o[m2][np]);
        }
    }
    __syncthreads();   // vT reads complete before outl overwrites the region
    #pragma unroll
    for (int m2 = 0; m2 < 2; ++m2) {
        int mt = half * 2 + m2;
        #pragma unroll
        for (int np = 0; np < 2; ++np)
            #pragma unroll
            for (int r = 0; r < 4; ++r)
                ldsX[(mt * 16 + mrow + r) * 132 + h * 32 + np * 16 + l15] = bfr(o[m2][np][r] * rinv[m2][r]);
    }
    __syncthreads();
    u16* op = attn_out + grow * 128 + seg * 16;
    *(uint4*)op = *(const uint4*)&ldsX[trow * 132 + seg * 16];
    *(uint4*)(op + 8) = *(const uint4*)&ldsX[trow * 132 + seg * 16 + 8];
}

// ---------- fused proj + residual + LN2 + MLP (r16 + packed b32 LDS writes) ----------
// fc1 N/K order permuted in prep so each lane owns adjacent hid pairs: GELU and
// y-transpose emit one pk2 + one ds_write_b32 per pair (halves converts+writes).
__global__ __launch_bounds__(256, 3) void swin_mlp_kernel(
    const u16* __restrict__ attn, const float* __restrict__ x,
    const u16* __restrict__ projws, const u16* __restrict__ wms,
    const float* __restrict__ projb, const float* __restrict__ g2, const float* __restrict__ b2,
    const float* __restrict__ f1b, const float* __restrict__ f2b, float* __restrict__ out)
{
    __shared__ __align__(16) u16 wbuf[2][8192];   // [8 fc1 tiles | 8 fc2 tiles] x 512
    __shared__ __align__(16) u16 sbuf[4][1152];   // per-wave [32][36] scratch

    int tid = threadIdx.x;
    int wave = tid >> 6, lane = tid & 63, l15 = lane & 15, lg = lane >> 4;
    long wbase = (long)blockIdx.x * 128 + wave * 32;

    // issue chunk-0 staging now (async; hides under proj + LN2)
    {
        const u16* src = wms + wave * 2048 + lane * 8;
        u16* dst = &wbuf[0][wave * 2048];
        #pragma unroll
        for (int i = 0; i < 4; ++i)
            gload16(src + i * 512, dst + i * 512);
    }

    // A-frags from attn_out (2 m-tiles)
    const u16* arow = attn + (wbase + l15) * 128 + lg * 8;
    bf16x8 aat[2][4];
    #pragma unroll
    for (int ks = 0; ks < 4; ++ks) {
        aat[0][ks] = *(const bf16x8*)(arow + ks * 32);
        aat[1][ks] = *(const bf16x8*)(arow + 2048 + ks * 32);
    }

    // proj GEMM: B-frags direct from global fragment tiles (L2-hot)
    f32x4 pacc[2][8];
    #pragma unroll
    for (int nt = 0; nt < 8; ++nt) {
        const u16* wp = projws + nt * 2048 + lane * 8;
        pacc[0][nt] = (f32x4){0.0f, 0.0f, 0.0f, 0.0f};
        pacc[1][nt] = (f32x4){0.0f, 0.0f, 0.0f, 0.0f};
        #pragma unroll
        for (int ks = 0; ks < 4; ++ks) {
            bf16x8 bw = *(const bf16x8*)(wp + ks * 512);
            pacc[0][nt] = MFMA(aat[0][ks], bw, pacc[0][nt]);
            pacc[1][nt] = MFMA(aat[1][ks], bw, pacc[1][nt]);
        }
    }

    // residual: xn = x + proj_out + projb
    #pragma unroll
    for (int nt = 0; nt < 8; ++nt) {
        float pb = projb[nt * 16 + l15];
        #pragma unroll
        for (int mt = 0; mt < 2; ++mt)
            #pragma unroll
            for (int r = 0; r < 4; ++r)
                pacc[mt][nt][r] += x[(wbase + mt * 16 + lg * 4 + r) * 128 + nt * 16 + l15] + pb;
    }
    // LN2
    float mu[2][4], rstd[2][4];
    #pragma unroll
    for (int mt = 0; mt < 2; ++mt)
        #pragma unroll
        for (int r = 0; r < 4; ++r) {
            float a = 0.0f, bq = 0.0f;
            #pragma unroll
            for (int nt = 0; nt < 8; ++nt) { a += pacc[mt][nt][r]; bq += pacc[mt][nt][r] * pacc[mt][nt][r]; }
            #pragma unroll
            for (int off = 1; off < 16; off <<= 1) { a += __shfl_xor(a, off); bq += __shfl_xor(bq, off); }
            mu[mt][r] = a * 0.0078125f;
            rstd[mt][r] = rsqrtf(bq * 0.0078125f - mu[mt][r] * mu[mt][r] + 1e-5f);
        }
    // y transpose: 4 passes; packed b32 writes at position-pairs (K-perm'd storage)
    u16* hb = (u16*)sbuf[wave];
    bf16x8 ay[2][4];
    #pragma unroll
    for (int p = 0; p < 4; ++p) {
        float gg0 = g2[p * 32 + l15],      bb0 = b2[p * 32 + l15];
        float gg1 = g2[p * 32 + 16 + l15], bb1 = b2[p * 32 + 16 + l15];
        #pragma unroll
        for (int mt = 0; mt < 2; ++mt)
            #pragma unroll
            for (int r = 0; r < 4; ++r) {
                float y0 = (pacc[mt][p * 2 + 0][r] - mu[mt][r]) * rstd[mt][r] * gg0 + bb0;
                float y1 = (pacc[mt][p * 2 + 1][r] - mu[mt][r]) * rstd[mt][r] * gg1 + bb1;
                *(u32*)&hb[(mt * 16 + lg * 4 + r) * 36 + 2 * l15] = pk2(y0, y1);
            }
        __builtin_amdgcn_sched_barrier(0);
        ay[0][p] = *(const bf16x8*)&hb[l15 * 36 + lg * 8];
        ay[1][p] = *(const bf16x8*)&hb[(16 + l15) * 36 + lg * 8];
        __builtin_amdgcn_sched_barrier(0);
    }
    // fold fc2 bias: pacc = xn + f2b; chunk-loop MFMAs accumulate on top
    #pragma unroll
    for (int nt = 0; nt < 8; ++nt) {
        float fb = f2b[nt * 16 + l15];
        #pragma unroll
        for (int mt = 0; mt < 2; ++mt)
            #pragma unroll
            for (int r = 0; r < 4; ++r)
                pacc[mt][nt][r] += fb;
    }
    __syncthreads();   // chunk 0 staged (vmcnt drained) & visible

    #pragma unroll 1
    for (int cc = 0; cc < 16; ++cc) {
        int cur = cc & 1;
        // prefetch chunk cc+1 (async; buf[cur^1] fully consumed before last barrier)
        if (cc < 15) {
            const u16* src = wms + (cc + 1) * 8192 + wave * 2048 + lane * 8;
            u16* dst = &wbuf[cur ^ 1][wave * 2048];
            #pragma unroll
            for (int i = 0; i < 4; ++i)
                gload16(src + i * 512, dst + i * 512);
        }
        // fc1 (K=128, N=32): 16 MFMAs
        f32x4 h[2][2];
        h[0][0] = h[0][1] = h[1][0] = h[1][1] = (f32x4){0.0f, 0.0f, 0.0f, 0.0f};
        #pragma unroll
        for (int n2 = 0; n2 < 2; ++n2)
            #pragma unroll
            for (int ks = 0; ks < 4; ++ks) {
                bf16x8 bw = *(const bf16x8*)&wbuf[cur][(n2 * 4 + ks) * 512 + lane * 8];
                h[0][n2] = MFMA(ay[0][ks], bw, h[0][n2]);
                h[1][n2] = MFMA(ay[1][ks], bw, h[1][n2]);
            }
        // GELU (poly) -> packed b32 writes (lane owns hid pair 2*l15, 2*l15+1)
        float2 fbp = *(const float2*)(f1b + cc * 32 + 2 * l15);
        #pragma unroll
        for (int mt = 0; mt < 2; ++mt)
            #pragma unroll
            for (int r = 0; r < 4; ++r) {
                float g0 = gelu_poly(h[mt][0][r] + fbp.x);
                float g1 = gelu_poly(h[mt][1][r] + fbp.y);
                *(u32*)&hb[(mt * 16 + lg * 4 + r) * 36 + 2 * l15] = pk2(g0, g1);
            }
        __builtin_amdgcn_sched_barrier(0);
        bf16x8 ah0 = *(const bf16x8*)&hb[l15 * 36 + lg * 8];
        bf16x8 ah1 = *(const bf16x8*)&hb[(16 + l15) * 36 + lg * 8];
        __builtin_amdgcn_sched_barrier(0);
        // fc2 (K=32): 16 MFMAs accumulating into pacc
        #pragma unroll
        for (int nt = 0; nt < 8; ++nt) {
            bf16x8 bw = *(const bf16x8*)&wbuf[cur][(8 + nt) * 512 + lane * 8];
            pacc[0][nt] = MFMA(ah0, bw, pacc[0][nt]);
            pacc[1][nt] = MFMA(ah1, bw, pacc[1][nt]);
        }
        __syncthreads();   // chunk cc+1 staged & all waves done with buf[cur]
    }
    // epilogue: pacc = xn + f2b + fc2_out
    #pragma unroll
    for (int nt = 0; nt < 8; ++nt)
        #pragma unroll
        for (int mt = 0; mt < 2; ++mt)
            #pragma unroll
            for (int r = 0; r < 4; ++r)
                out[(wbase + mt * 16 + lg * 4 + r) * 128 + nt * 16 + l15] = pacc[mt][nt][r];
}

extern "C" void kernel_launch(void* const* d_in, const int* in_sizes, int n_in,
                              void* d_out, int out_size, void* d_ws, size_t ws_size,
                              hipStream_t stream)
{
    const float* x     = (const float*)d_in[0];
    const float* n1g   = (const float*)d_in[1];
    const float* n1b   = (const float*)d_in[2];
    const float* qkvw  = (const float*)d_in[3];
    const float* qkvb  = (const float*)d_in[4];
    const float* rpb   = (const float*)d_in[5];
    const float* projw = (const float*)d_in[6];
    const float* projb = (const float*)d_in[7];
    const float* n2g   = (const float*)d_in[8];
    const float* n2b   = (const float*)d_in[9];
    const float* f1w   = (const float*)d_in[10];
    const float* f1b   = (const float*)d_in[11];
    const float* f2w   = (const float*)d_in[12];
    const float* f2b   = (const float*)d_in[13];

    char* ws = (char*)d_ws;
    u16* attn_buf = (u16*)ws;                                  // 67,108,864 B
    u16* wb = (u16*)(ws + 67108864);                           // 212992 u16 = 425,984 B
    float* bias_lane = (float*)(ws + 67108864 + 425984);       // 262,144 B
    u16* qkvwb  = wb;                                          // [0,49152)
    u16* projws = wb + 49152;                                  // [49152,81920)
    u16* wms    = wb + 81920;                                  // [81920,212992)

    swin_prep_kernel<<<1088, 256, 0, stream>>>(qkvw, projw, f1w, f2w, rpb, wb, bias_lane);
    swin_attn_kernel<<<4096, 512, 0, stream>>>(x, n1g, n1b, qkvb, qkvwb, bias_lane, attn_buf);
    swin_mlp_kernel<<<2048, 256, 0, stream>>>(attn_buf, x, projws, wms,
                                              projb, n2g, n2b, f1b, f2b, (float*)d_out);
}

// Round 19
// 235.059 us; speedup vs baseline: 1.0556x; 1.0556x over previous
//
#include <hip/hip_runtime.h>
#include <hip/hip_bf16.h>

typedef unsigned short u16;
typedef unsigned int u32;
typedef __attribute__((ext_vector_type(8))) short bf16x8;
typedef __attribute__((ext_vector_type(4))) float f32x4;

__device__ __forceinline__ u32 fbits(float f) { union { float f; u32 u; } a; a.f = f; return a.u; }
__device__ __forceinline__ u16 f2bf(float f) {   // RNE (prep only, cold)
    u32 u = fbits(f);
    return (u16)((u + 0x7FFFu + ((u >> 16) & 1u)) >> 16);
}
// hot-path round-half-up conversions
__device__ __forceinline__ u16 bfr(float f) { return (u16)((fbits(f) + 0x8000u) >> 16); }
__device__ __forceinline__ u32 pk2(float lo, float hi) {
    return __builtin_amdgcn_perm(fbits(hi) + 0x8000u, fbits(lo) + 0x8000u, 0x07060302u);
}
__device__ __forceinline__ float bf2f(u16 b) {
    union { u32 u; float f; } a; a.u = ((u32)b) << 16; return a.f;
}
// transcendental-free GELU: t*sigma(1.702t), odd quintic, clamp +-3.
__device__ __forceinline__ float gelu_poly(float t) {
    float u = fminf(3.0f, fmaxf(-3.0f, t));
    float u2 = u * u;
    float w = fmaf(u2, 0.00319581f, -0.0550159f);
    w = fmaf(u2, w, 0.401174f);
    float sg = fmaf(u, w, 0.5f);
    return t * sg;
}

#define MFMA(a, b, c) __builtin_amdgcn_mfma_f32_16x16x32_bf16(a, b, c, 0, 0, 0)

// async global->LDS, 16B per lane; dst must be wave-uniform (HW adds lane*16)
__device__ __forceinline__ void gload16(const u16* g, u16* l) {
    __builtin_amdgcn_global_load_lds(
        (const __attribute__((address_space(1))) void*)g,
        (__attribute__((address_space(3))) void*)l, 16, 0, 0);
}

// ---------- prep ----------
// wout: [0,49152) qkv row-major | [49152,81920) projws fragment-tile order
//       [81920,212992) wms: 16 chunks x (8 fc1 tiles + 8 fc2 tiles) x 512
// fc1 tiles (A-operand for h^T = W1 x y^T): tile mh*4+ks, elem(lane,e) =
//   W1[chunk*32 + mh*16 + (lane&15)][ks*32 + (lane>>4)*8 + e]   (natural order)
// fc2 tiles: K-order PERMUTED to match the register-packed A-frag from h^T's
//   D-layout: position p=(lane>>4)*8+e holds hid = e<4 ? lg*4+e : 16+lg*4+e-4.
// bias_lane pre-scaled by 1/ln2 (max-free exp2 softmax).
__global__ void swin_prep_kernel(const float* __restrict__ qkv_w, const float* __restrict__ proj_w,
                                 const float* __restrict__ fc1_w, const float* __restrict__ fc2_w,
                                 const float* __restrict__ rpb, u16* __restrict__ wout,
                                 float* __restrict__ bias_lane)
{
    int idx = blockIdx.x * 256 + threadIdx.x;
    if (idx < 49152) wout[idx] = f2bf(qkv_w[idx]);
    else if (idx < 81920) {
        int j = idx - 49152;
        int tile = j >> 9, lane = (j >> 3) & 63, e = j & 7;
        int nt = tile >> 2, ks = tile & 3;
        wout[idx] = f2bf(proj_w[(nt * 16 + (lane & 15)) * 128 + ks * 32 + (lane >> 4) * 8 + e]);
    } else if (idx < 212992) {
        int j = idx - 81920;
        int chunk = j >> 13, rest = j & 8191;
        int tile = rest >> 9, lane = (rest >> 3) & 63, e = rest & 7;
        int lg = lane >> 4;
        float v;
        if (tile < 8) {
            int mh = tile >> 2, ks = tile & 3;
            v = fc1_w[(chunk * 32 + mh * 16 + (lane & 15)) * 128 + ks * 32 + lg * 8 + e];
        } else {
            int nt = tile - 8;
            int hid = (e < 4) ? (lg * 4 + e) : (16 + lg * 4 + (e - 4));
            v = fc2_w[(nt * 16 + (lane & 15)) * 512 + chunk * 32 + hid];
        }
        wout[idx] = f2bf(v);
    } else {
        int t = idx - 212992;  // < 65536
        int r = t & 3, lane = (t >> 2) & 63, nt = (t >> 8) & 3, mt = (t >> 10) & 3;
        int h = (t >> 12) & 3, v = (t >> 14) & 3;
        int i = mt * 16 + ((lane >> 4) << 2) + r;
        int j = nt * 16 + (lane & 15);
        int ri = i >> 3, ci = i & 7, rj = j >> 3, cj = j & 7;
        int rpi = (ri - rj + 7) * 15 + (ci - cj + 7);
        float bv = rpb[rpi * 4 + h];
        int vh = v >> 1, vw = v & 1;
        int regi = (vh ? (ri < 4 ? 1 : 2) : 0) * 3 + (vw ? (ci < 4 ? 1 : 2) : 0);
        int regj = (vh ? (rj < 4 ? 1 : 2) : 0) * 3 + (vw ? (cj < 4 ? 1 : 2) : 0);
        if (regi != regj) bv -= 100.0f;
        bias_lane[t] = bv * 1.4426950408889634f;   // pre-scale by 1/ln2 for exp2
    }
}

// ---------- fused LN1 + qkv + windowed attention (r17 verbatim) ----------
__global__ __launch_bounds__(512, 4) void swin_attn_kernel(
    const float* __restrict__ x, const float* __restrict__ g1, const float* __restrict__ b1,
    const float* __restrict__ qkvb, const u16* __restrict__ qkvw,
    const float* __restrict__ bias_lane, u16* __restrict__ attn_out)
{
    __shared__ __align__(16) u16 ldsX[8448];     // xln[64][132] | vT swz | outl[64][132]
    __shared__ __align__(16) u16 ldsQK[17408];   // q|k, then P[4][64][68]
    __shared__ float sb[640];                    // g1 | b1 | qkv_b

    int tid = threadIdx.x;
    int wid = blockIdx.x;
    int bb_ = wid >> 10, wh = (wid >> 5) & 31, ww = wid & 31;

    for (int i = tid; i < 640; i += 512) {
        float v;
        if (i < 128) v = g1[i];
        else if (i < 256) v = b1[i - 128];
        else v = qkvb[i - 256];
        sb[i] = v;
    }

    // ---- phase 1: gather rolled x rows, LN1 -> xln ----
    int trow = tid >> 3, seg = tid & 7;
    int rn = trow >> 3, cn = trow & 7;
    int srow = (wh * 8 + rn + 4) & 255;
    int scol = (ww * 8 + cn + 4) & 255;
    long grow = (long)bb_ * 65536 + srow * 256 + scol;
    const float4* xrow = (const float4*)(x + grow * 128 + seg * 16);
    float4 xv[4];
    #pragma unroll
    for (int i = 0; i < 4; ++i) xv[i] = xrow[i];
    __syncthreads();  // sb visible

    float s1 = 0.0f, s2 = 0.0f;
    #pragma unroll
    for (int i = 0; i < 4; ++i) {
        float4 v = xv[i];
        s1 += v.x + v.y + v.z + v.w;
        s2 += v.x * v.x + v.y * v.y + v.z * v.z + v.w * v.w;
    }
    #pragma unroll
    for (int off = 1; off < 8; off <<= 1) { s1 += __shfl_xor(s1, off); s2 += __shfl_xor(s2, off); }
    float mu = s1 * 0.0078125f;
    float rstd = rsqrtf(s2 * 0.0078125f - mu * mu + 1e-5f);
    {
        u32 pk[8];
        #pragma unroll
        for (int i = 0; i < 4; ++i) {
            float vv[4] = {xv[i].x, xv[i].y, xv[i].z, xv[i].w};
            float y0, y1, y2, y3;
            {
                int c = seg * 16 + i * 4;
                y0 = (vv[0] - mu) * rstd * sb[c + 0] + sb[128 + c + 0];
                y1 = (vv[1] - mu) * rstd * sb[c + 1] + sb[128 + c + 1];
                y2 = (vv[2] - mu) * rstd * sb[c + 2] + sb[128 + c + 2];
                y3 = (vv[3] - mu) * rstd * sb[c + 3] + sb[128 + c + 3];
            }
            pk[i * 2]     = pk2(y0, y1);
            pk[i * 2 + 1] = pk2(y2, y3);
        }
        *(uint4*)&ldsX[trow * 132 + seg * 16] = *(uint4*)&pk[0];
        *(uint4*)&ldsX[trow * 132 + seg * 16 + 8] = *(uint4*)&pk[4];
    }
    __syncthreads();

    // ---- phase 2: qkv GEMM (M=64,N=384,K=128); wave w owns nt = 3w..3w+2 ----
    int wave = tid >> 6, lane = tid & 63, l15 = lane & 15, lg = lane >> 4;
    int mrow = lg * 4;
    bf16x8 afr[4][4];
    #pragma unroll
    for (int mt = 0; mt < 4; ++mt)
        #pragma unroll
        for (int ks = 0; ks < 4; ++ks)
            afr[mt][ks] = *(const bf16x8*)&ldsX[(mt * 16 + l15) * 132 + ks * 32 + lg * 8];
    __syncthreads();   // xln fully consumed; region becomes vT
    #pragma unroll 1
    for (int nn = 0; nn < 3; ++nn) {
        int nt = wave * 3 + nn;
        int n = nt * 16 + l15;
        const u16* wp = qkvw + n * 128 + lg * 8;
        bf16x8 bfr_[4];
        #pragma unroll
        for (int ks = 0; ks < 4; ++ks) bfr_[ks] = *(const bf16x8*)(wp + ks * 32);
        f32x4 acc[4];
        #pragma unroll
        for (int mt = 0; mt < 4; ++mt) acc[mt] = (f32x4){0.0f, 0.0f, 0.0f, 0.0f};
        #pragma unroll
        for (int ks = 0; ks < 4; ++ks)
            #pragma unroll
            for (int mt = 0; mt < 4; ++mt)
                acc[mt] = MFMA(afr[mt][ks], bfr_[ks], acc[mt]);
        float bias = sb[256 + n];
        if (n < 128) {
            #pragma unroll
            for (int mt = 0; mt < 4; ++mt)
                #pragma unroll
                for (int r = 0; r < 4; ++r)
                    ldsQK[(mt * 16 + mrow + r) * 132 + n] = bfr(acc[mt][r] + bias);
        } else if (n < 256) {
            #pragma unroll
            for (int mt = 0; mt < 4; ++mt)
                #pragma unroll
                for (int r = 0; r < 4; ++r)
                    ldsQK[8448 + (mt * 16 + mrow + r) * 132 + (n - 128)] = bfr(acc[mt][r] + bias);
        } else {
            int row = n - 256;                      // v dim index 0..127
            int sw = (row & 7) << 4;                // T2 XOR swizzle (16B granules)
            #pragma unroll
            for (int mt = 0; mt < 4; ++mt) {        // v^T: 4 consecutive tokens -> uint2
                uint2 pv;
                pv.x = pk2(acc[mt][0] + bias, acc[mt][1] + bias);
                pv.y = pk2(acc[mt][2] + bias, acc[mt][3] + bias);
                int cb = ((mt * 16 + mrow) * 2) ^ sw;
                *(uint2*)((char*)ldsX + row * 128 + cb) = pv;
            }
        }
    }
    __syncthreads();

    // ---- phase 3: attention; wave pair per head; max-free exp2 softmax ----
    int h = wave >> 1, half = wave & 1;
    int v4 = ((wh == 31) ? 2 : 0) | ((ww == 31) ? 1 : 0);
    const float4* blp = (const float4*)bias_lane;
    bf16x8 bk[4];
    #pragma unroll
    for (int nt = 0; nt < 4; ++nt)
        bk[nt] = *(const bf16x8*)&ldsQK[8448 + (nt * 16 + l15) * 132 + h * 32 + lg * 8];
    f32x4 sS[2][4];
    #pragma unroll
    for (int m2 = 0; m2 < 2; ++m2) {
        int mt = half * 2 + m2;
        bf16x8 aq = *(const bf16x8*)&ldsQK[(mt * 16 + l15) * 132 + h * 32 + lg * 8];
        #pragma unroll
        for (int nt = 0; nt < 4; ++nt) {
            f32x4 z = (f32x4){0.0f, 0.0f, 0.0f, 0.0f};
            z = MFMA(aq, bk[nt], z);
            float4 bl = blp[((v4 * 4 + h) * 16 + mt * 4 + nt) * 64 + lane];
            sS[m2][nt][0] = z[0] * 0.2550349f + bl.x;
            sS[m2][nt][1] = z[1] * 0.2550349f + bl.y;
            sS[m2][nt][2] = z[2] * 0.2550349f + bl.z;
            sS[m2][nt][3] = z[3] * 0.2550349f + bl.w;
        }
    }
    float rinv[2][4];
    #pragma unroll
    for (int m2 = 0; m2 < 2; ++m2) {
        #pragma unroll
        for (int r = 0; r < 4; ++r) {
            float sum = 0.0f;
            #pragma unroll
            for (int nt = 0; nt < 4; ++nt) {
                float p = exp2f(sS[m2][nt][r]);   // no max-shift needed (|S|<~3)
                sS[m2][nt][r] = p;
                sum += p;
            }
            #pragma unroll
            for (int off = 1; off < 16; off <<= 1) sum += __shfl_xor(sum, off);
            rinv[m2][r] = __builtin_amdgcn_rcpf(sum);
        }
    }
    __syncthreads();   // all q/k reads complete before P overlays the region
    #pragma unroll
    for (int m2 = 0; m2 < 2; ++m2) {
        int mt = half * 2 + m2;
        #pragma unroll
        for (int nt = 0; nt < 4; ++nt)
            #pragma unroll
            for (int r = 0; r < 4; ++r)
                ldsQK[h * 4352 + (mt * 16 + mrow + r) * 68 + nt * 16 + l15] = bfr(sS[m2][nt][r]);
    }
    __syncthreads();

    // PV: out = P @ V (V from swizzled region)
    f32x4 o[2][2];
    #pragma unroll
    for (int m2 = 0; m2 < 2; ++m2)
        #pragma unroll
        for (int np = 0; np < 2; ++np) o[m2][np] = (f32x4){0.0f, 0.0f, 0.0f, 0.0f};
    #pragma unroll
    for (int kt = 0; kt < 2; ++kt) {
        bf16x8 pa[2];
        #pragma unroll
        for (int m2 = 0; m2 < 2; ++m2) {
            int mt = half * 2 + m2;
            pa[m2] = *(const bf16x8*)&ldsQK[h * 4352 + (mt * 16 + l15) * 68 + kt * 32 + lg * 8];
        }
        #pragma unroll
        for (int np = 0; np < 2; ++np) {
            int vr = h * 32 + np * 16 + l15;
            int cb = (kt * 64 + lg * 16) ^ ((vr & 7) << 4);
            bf16x8 bv = *(const bf16x8*)((const char*)ldsX + vr * 128 + cb);
            #pragma unroll
            for (int m2 = 0; m2 < 2; ++m2)
                o[m2][np] = MFMA(pa[m2], bv, o[m2][np]);
        }
    }
    __syncthreads();   // vT reads complete before outl overwrites the region
    #pragma unroll
    for (int m2 = 0; m2 < 2; ++m2) {
        int mt = half * 2 + m2;
        #pragma unroll
        for (int np = 0; np < 2; ++np)
            #pragma unroll
            for (int r = 0; r < 4; ++r)
                ldsX[(mt * 16 + mrow + r) * 132 + h * 32 + np * 16 + l15] = bfr(o[m2][np][r] * rinv[m2][r]);
    }
    __syncthreads();
    u16* op = attn_out + grow * 128 + seg * 16;
    *(uint4*)op = *(const uint4*)&ldsX[trow * 132 + seg * 16];
    *(uint4*)(op + 8) = *(const uint4*)&ldsX[trow * 132 + seg * 16 + 8];
}

// ---------- fused proj + residual + LN2 + MLP (h^T operand-swap: no LDS roundtrip) ----------
// fc1 computed as h^T = MFMA(A=W1-frag, B=y-frag): D lane l15 = token, rows = hid.
// GELU in registers; fc2 A-frag packed from D regs (4x pk2); fc2 K-order permuted
// in prep to match. Chunk loop has ZERO LDS scratch ops (16 b128 weight reads only).
__global__ __launch_bounds__(256, 3) void swin_mlp_kernel(
    const u16* __restrict__ attn, const float* __restrict__ x,
    const u16* __restrict__ projws, const u16* __restrict__ wms,
    const float* __restrict__ projb, const float* __restrict__ g2, const float* __restrict__ b2,
    const float* __restrict__ f1b, const float* __restrict__ f2b, float* __restrict__ out)
{
    __shared__ __align__(16) u16 wbuf[2][8192];   // [8 fc1 tiles | 8 fc2 tiles] x 512
    __shared__ __align__(16) u16 sbuf[4][576];    // per-wave [16][36] (prologue only)

    int tid = threadIdx.x;
    int wave = tid >> 6, lane = tid & 63, l15 = lane & 15, lg = lane >> 4;
    long wbase = (long)blockIdx.x * 128 + wave * 32;

    // issue chunk-0 staging now (async; hides under proj + LN2)
    {
        const u16* src = wms + wave * 2048 + lane * 8;
        u16* dst = &wbuf[0][wave * 2048];
        #pragma unroll
        for (int i = 0; i < 4; ++i)
            gload16(src + i * 512, dst + i * 512);
    }

    // A-frags from attn_out (2 m-tiles)
    const u16* arow = attn + (wbase + l15) * 128 + lg * 8;
    bf16x8 aat[2][4];
    #pragma unroll
    for (int ks = 0; ks < 4; ++ks) {
        aat[0][ks] = *(const bf16x8*)(arow + ks * 32);
        aat[1][ks] = *(const bf16x8*)(arow + 2048 + ks * 32);
    }

    // proj GEMM: B-frags direct from global fragment tiles (L2-hot)
    f32x4 pacc[2][8];
    #pragma unroll
    for (int nt = 0; nt < 8; ++nt) {
        const u16* wp = projws + nt * 2048 + lane * 8;
        pacc[0][nt] = (f32x4){0.0f, 0.0f, 0.0f, 0.0f};
        pacc[1][nt] = (f32x4){0.0f, 0.0f, 0.0f, 0.0f};
        #pragma unroll
        for (int ks = 0; ks < 4; ++ks) {
            bf16x8 bw = *(const bf16x8*)(wp + ks * 512);
            pacc[0][nt] = MFMA(aat[0][ks], bw, pacc[0][nt]);
            pacc[1][nt] = MFMA(aat[1][ks], bw, pacc[1][nt]);
        }
    }

    // residual: xn = x + proj_out + projb
    #pragma unroll
    for (int nt = 0; nt < 8; ++nt) {
        float pb = projb[nt * 16 + l15];
        #pragma unroll
        for (int mt = 0; mt < 2; ++mt)
            #pragma unroll
            for (int r = 0; r < 4; ++r)
                pacc[mt][nt][r] += x[(wbase + mt * 16 + lg * 4 + r) * 128 + nt * 16 + l15] + pb;
    }
    // LN2
    float mu[2][4], rstd[2][4];
    #pragma unroll
    for (int mt = 0; mt < 2; ++mt)
        #pragma unroll
        for (int r = 0; r < 4; ++r) {
            float a = 0.0f, bq = 0.0f;
            #pragma unroll
            for (int nt = 0; nt < 8; ++nt) { a += pacc[mt][nt][r]; bq += pacc[mt][nt][r] * pacc[mt][nt][r]; }
            #pragma unroll
            for (int off = 1; off < 16; off <<= 1) { a += __shfl_xor(a, off); bq += __shfl_xor(bq, off); }
            mu[mt][r] = a * 0.0078125f;
            rstd[mt][r] = rsqrtf(bq * 0.0078125f - mu[mt][r] * mu[mt][r] + 1e-5f);
        }
    // y transpose (prologue only): 4 K-slices x 2 m-tiles via [16][36] scratch
    u16* hb = (u16*)sbuf[wave];
    bf16x8 ay[2][4];
    #pragma unroll
    for (int p = 0; p < 4; ++p) {
        #pragma unroll
        for (int mt = 0; mt < 2; ++mt) {
            #pragma unroll
            for (int n2 = 0; n2 < 2; ++n2) {
                int c = p * 32 + n2 * 16 + l15;
                float gg = g2[c], bb = b2[c];
                int nt = p * 2 + n2;
                #pragma unroll
                for (int r = 0; r < 4; ++r)
                    hb[(lg * 4 + r) * 36 + n2 * 16 + l15] =
                        bfr((pacc[mt][nt][r] - mu[mt][r]) * rstd[mt][r] * gg + bb);
            }
            __builtin_amdgcn_sched_barrier(0);
            ay[mt][p] = *(const bf16x8*)&hb[l15 * 36 + lg * 8];
            __builtin_amdgcn_sched_barrier(0);
        }
    }
    // fold fc2 bias: pacc = xn + f2b; chunk-loop MFMAs accumulate on top
    #pragma unroll
    for (int nt = 0; nt < 8; ++nt) {
        float fb = f2b[nt * 16 + l15];
        #pragma unroll
        for (int mt = 0; mt < 2; ++mt)
            #pragma unroll
            for (int r = 0; r < 4; ++r)
                pacc[mt][nt][r] += fb;
    }
    __syncthreads();   // chunk 0 staged (vmcnt drained) & visible

    #pragma unroll 1
    for (int cc = 0; cc < 16; ++cc) {
        int cur = cc & 1;
        // prefetch chunk cc+1 (async; buf[cur^1] fully consumed before last barrier)
        if (cc < 15) {
            const u16* src = wms + (cc + 1) * 8192 + wave * 2048 + lane * 8;
            u16* dst = &wbuf[cur ^ 1][wave * 2048];
            #pragma unroll
            for (int i = 0; i < 4; ++i)
                gload16(src + i * 512, dst + i * 512);
        }
        // fc1 as h^T = MFMA(W1-frag, y-frag): D lane l15 = token, rows = hid
        // h[mt][mh]: token tile mt (B=ay[mt]), hid tile mh (A=W1 tile mh*4+ks)
        f32x4 h[2][2];
        h[0][0] = h[0][1] = h[1][0] = h[1][1] = (f32x4){0.0f, 0.0f, 0.0f, 0.0f};
        #pragma unroll
        for (int mh = 0; mh < 2; ++mh)
            #pragma unroll
            for (int ks = 0; ks < 4; ++ks) {
                bf16x8 w1 = *(const bf16x8*)&wbuf[cur][(mh * 4 + ks) * 512 + lane * 8];
                h[0][mh] = MFMA(w1, ay[0][ks], h[0][mh]);
                h[1][mh] = MFMA(w1, ay[1][ks], h[1][mh]);
            }
        // GELU in registers; pack fc2 A-frags (lane holds hids {lg*4+r, 16+lg*4+r})
        float4 fb0 = *(const float4*)(f1b + cc * 32 + lg * 4);
        float4 fb1 = *(const float4*)(f1b + cc * 32 + 16 + lg * 4);
        float b0[4] = {fb0.x, fb0.y, fb0.z, fb0.w};
        float b1[4] = {fb1.x, fb1.y, fb1.z, fb1.w};
        bf16x8 ah[2];
        #pragma unroll
        for (int mt = 0; mt < 2; ++mt) {
            float g0[4], g1[4];
            #pragma unroll
            for (int r = 0; r < 4; ++r) {
                g0[r] = gelu_poly(h[mt][0][r] + b0[r]);
                g1[r] = gelu_poly(h[mt][1][r] + b1[r]);
            }
            union { u32 w[4]; bf16x8 v; } u_;
            u_.w[0] = pk2(g0[0], g0[1]);
            u_.w[1] = pk2(g0[2], g0[3]);
            u_.w[2] = pk2(g1[0], g1[1]);
            u_.w[3] = pk2(g1[2], g1[3]);
            ah[mt] = u_.v;
        }
        // fc2 (K=32, permuted): 16 MFMAs accumulating into pacc
        #pragma unroll
        for (int nt = 0; nt < 8; ++nt) {
            bf16x8 bw = *(const bf16x8*)&wbuf[cur][(8 + nt) * 512 + lane * 8];
            pacc[0][nt] = MFMA(ah[0], bw, pacc[0][nt]);
            pacc[1][nt] = MFMA(ah[1], bw, pacc[1][nt]);
        }
        __syncthreads();   // chunk cc+1 staged & all waves done with buf[cur]
    }
    // epilogue: pacc = xn + f2b + fc2_out
    #pragma unroll
    for (int nt = 0; nt < 8; ++nt)
        #pragma unroll
        for (int mt = 0; mt < 2; ++mt)
            #pragma unroll
            for (int r = 0; r < 4; ++r)
                out[(wbase + mt * 16 + lg * 4 + r) * 128 + nt * 16 + l15] = pacc[mt][nt][r];
}

extern "C" void kernel_launch(void* const* d_in, const int* in_sizes, int n_in,
                              void* d_out, int out_size, void* d_ws, size_t ws_size,
                              hipStream_t stream)
{
    const float* x     = (const float*)d_in[0];
    const float* n1g   = (const float*)d_in[1];
    const float* n1b   = (const float*)d_in[2];
    const float* qkvw  = (const float*)d_in[3];
    const float* qkvb  = (const float*)d_in[4];
    const float* rpb   = (const float*)d_in[5];
    const float* projw = (const float*)d_in[6];
    const float* projb = (const float*)d_in[7];
    const float* n2g   = (const float*)d_in[8];
    const float* n2b   = (const float*)d_in[9];
    const float* f1w   = (const float*)d_in[10];
    const float* f1b   = (const float*)d_in[11];
    const float* f2w   = (const float*)d_in[12];
    const float* f2b   = (const float*)d_in[13];

    char* ws = (char*)d_ws;
    u16* attn_buf = (u16*)ws;                                  // 67,108,864 B
    u16* wb = (u16*)(ws + 67108864);                           // 212992 u16 = 425,984 B
    float* bias_lane = (float*)(ws + 67108864 + 425984);       // 262,144 B
    u16* qkvwb  = wb;                                          // [0,49152)
    u16* projws = wb + 49152;                                  // [49152,81920)
    u16* wms    = wb + 81920;                                  // [81920,212992)

    swin_prep_kernel<<<1088, 256, 0, stream>>>(qkvw, projw, f1w, f2w, rpb, wb, bias_lane);
    swin_attn_kernel<<<4096, 512, 0, stream>>>(x, n1g, n1b, qkvb, qkvwb, bias_lane, attn_buf);
    swin_mlp_kernel<<<2048, 256, 0, stream>>>(attn_buf, x, projws, wms,
                                              projb, n2g, n2b, f1b, f2b, (float*)d_out);
}

// Round 20
// 230.638 us; speedup vs baseline: 1.0758x; 1.0192x over previous
//
#include <hip/hip_runtime.h>
#include <hip/hip_bf16.h>

typedef unsigned short u16;
typedef unsigned int u32;
typedef __attribute__((ext_vector_type(8))) short bf16x8;
typedef __attribute__((ext_vector_type(4))) float f32x4;

__device__ __forceinline__ u32 fbits(float f) { union { float f; u32 u; } a; a.f = f; return a.u; }
__device__ __forceinline__ u16 f2bf(float f) {   // RNE (prep only, cold)
    u32 u = fbits(f);
    return (u16)((u + 0x7FFFu + ((u >> 16) & 1u)) >> 16);
}
// hot-path round-half-up conversions
__device__ __forceinline__ u16 bfr(float f) { return (u16)((fbits(f) + 0x8000u) >> 16); }
__device__ __forceinline__ u32 pk2(float lo, float hi) {
    return __builtin_amdgcn_perm(fbits(hi) + 0x8000u, fbits(lo) + 0x8000u, 0x07060302u);
}
__device__ __forceinline__ float bf2f(u16 b) {
    union { u32 u; float f; } a; a.u = ((u32)b) << 16; return a.f;
}
// transcendental-free GELU: t*sigma(1.702t), odd quintic, clamp +-3.
__device__ __forceinline__ float gelu_poly(float t) {
    float u = fminf(3.0f, fmaxf(-3.0f, t));
    float u2 = u * u;
    float w = fmaf(u2, 0.00319581f, -0.0550159f);
    w = fmaf(u2, w, 0.401174f);
    float sg = fmaf(u, w, 0.5f);
    return t * sg;
}

#define MFMA(a, b, c) __builtin_amdgcn_mfma_f32_16x16x32_bf16(a, b, c, 0, 0, 0)

// async global->LDS, 16B per lane; dst must be wave-uniform (HW adds lane*16)
__device__ __forceinline__ void gload16(const u16* g, u16* l) {
    __builtin_amdgcn_global_load_lds(
        (const __attribute__((address_space(1))) void*)g,
        (__attribute__((address_space(3))) void*)l, 16, 0, 0);
}

// ---------- prep ----------
// wout: [0,49152) qkv row-major | [49152,81920) projws fragment-tile order
//       [81920,212992) wms: 16 chunks x (8 fc1 tiles + 8 fc2 tiles) x 512
// fc1 tiles (A-operand for h^T): natural order (r19). fc2 tiles: K-permuted (r19).
// bias_lane: built for SWAPPED QK^T (S^T = K x Q): D col = query, D row = key:
//   query = mt*16 + (lane&15), key = nt*16 + (lane>>4)*4 + r. Pre-scaled by 1/ln2.
__global__ void swin_prep_kernel(const float* __restrict__ qkv_w, const float* __restrict__ proj_w,
                                 const float* __restrict__ fc1_w, const float* __restrict__ fc2_w,
                                 const float* __restrict__ rpb, u16* __restrict__ wout,
                                 float* __restrict__ bias_lane)
{
    int idx = blockIdx.x * 256 + threadIdx.x;
    if (idx < 49152) wout[idx] = f2bf(qkv_w[idx]);
    else if (idx < 81920) {
        int j = idx - 49152;
        int tile = j >> 9, lane = (j >> 3) & 63, e = j & 7;
        int nt = tile >> 2, ks = tile & 3;
        wout[idx] = f2bf(proj_w[(nt * 16 + (lane & 15)) * 128 + ks * 32 + (lane >> 4) * 8 + e]);
    } else if (idx < 212992) {
        int j = idx - 81920;
        int chunk = j >> 13, rest = j & 8191;
        int tile = rest >> 9, lane = (rest >> 3) & 63, e = rest & 7;
        int lg = lane >> 4;
        float v;
        if (tile < 8) {
            int mh = tile >> 2, ks = tile & 3;
            v = fc1_w[(chunk * 32 + mh * 16 + (lane & 15)) * 128 + ks * 32 + lg * 8 + e];
        } else {
            int nt = tile - 8;
            int hid = (e < 4) ? (lg * 4 + e) : (16 + lg * 4 + (e - 4));
            v = fc2_w[(nt * 16 + (lane & 15)) * 512 + chunk * 32 + hid];
        }
        wout[idx] = f2bf(v);
    } else {
        int t = idx - 212992;  // < 65536
        int r = t & 3, lane = (t >> 2) & 63, nt = (t >> 8) & 3, mt = (t >> 10) & 3;
        int h = (t >> 12) & 3, v = (t >> 14) & 3;
        int i = mt * 16 + (lane & 15);              // query (D col after swap)
        int j = nt * 16 + ((lane >> 4) << 2) + r;   // key (D row after swap)
        int ri = i >> 3, ci = i & 7, rj = j >> 3, cj = j & 7;
        int rpi = (ri - rj + 7) * 15 + (ci - cj + 7);
        float bv = rpb[rpi * 4 + h];
        int vh = v >> 1, vw = v & 1;
        int regi = (vh ? (ri < 4 ? 1 : 2) : 0) * 3 + (vw ? (ci < 4 ? 1 : 2) : 0);
        int regj = (vh ? (rj < 4 ? 1 : 2) : 0) * 3 + (vw ? (cj < 4 ? 1 : 2) : 0);
        if (regi != regj) bv -= 100.0f;
        bias_lane[t] = bv * 1.4426950408889634f;   // pre-scale by 1/ln2 for exp2
    }
}

// ---------- fused LN1 + qkv + windowed attention ----------
// Swapped QK^T (S^T = MFMA(K,Q)): P lives in registers in exactly the PV A-frag
// layout -> zero P LDS round-trip, 2 fewer barriers. vT columns permuted so the
// B-operand K-order matches the packed A-frag; rinv applied at O via __shfl.
__global__ __launch_bounds__(512, 4) void swin_attn_kernel(
    const float* __restrict__ x, const float* __restrict__ g1, const float* __restrict__ b1,
    const float* __restrict__ qkvb, const u16* __restrict__ qkvw,
    const float* __restrict__ bias_lane, u16* __restrict__ attn_out)
{
    __shared__ __align__(16) u16 ldsX[8448];     // xln[64][132] | vT swz | outl[64][132]
    __shared__ __align__(16) u16 ldsQK[16896];   // q[64][132] | k[64][132]
    __shared__ float sb[640];                    // g1 | b1 | qkv_b

    int tid = threadIdx.x;
    int wid = blockIdx.x;
    int bb_ = wid >> 10, wh = (wid >> 5) & 31, ww = wid & 31;

    for (int i = tid; i < 640; i += 512) {
        float v;
        if (i < 128) v = g1[i];
        else if (i < 256) v = b1[i - 128];
        else v = qkvb[i - 256];
        sb[i] = v;
    }

    // ---- phase 1: gather rolled x rows, LN1 -> xln ----
    int trow = tid >> 3, seg = tid & 7;
    int rn = trow >> 3, cn = trow & 7;
    int srow = (wh * 8 + rn + 4) & 255;
    int scol = (ww * 8 + cn + 4) & 255;
    long grow = (long)bb_ * 65536 + srow * 256 + scol;
    const float4* xrow = (const float4*)(x + grow * 128 + seg * 16);
    float4 xv[4];
    #pragma unroll
    for (int i = 0; i < 4; ++i) xv[i] = xrow[i];
    __syncthreads();  // sb visible

    float s1 = 0.0f, s2 = 0.0f;
    #pragma unroll
    for (int i = 0; i < 4; ++i) {
        float4 v = xv[i];
        s1 += v.x + v.y + v.z + v.w;
        s2 += v.x * v.x + v.y * v.y + v.z * v.z + v.w * v.w;
    }
    #pragma unroll
    for (int off = 1; off < 8; off <<= 1) { s1 += __shfl_xor(s1, off); s2 += __shfl_xor(s2, off); }
    float mu = s1 * 0.0078125f;
    float rstd = rsqrtf(s2 * 0.0078125f - mu * mu + 1e-5f);
    {
        u32 pk[8];
        #pragma unroll
        for (int i = 0; i < 4; ++i) {
            float vv[4] = {xv[i].x, xv[i].y, xv[i].z, xv[i].w};
            float y0, y1, y2, y3;
            {
                int c = seg * 16 + i * 4;
                y0 = (vv[0] - mu) * rstd * sb[c + 0] + sb[128 + c + 0];
                y1 = (vv[1] - mu) * rstd * sb[c + 1] + sb[128 + c + 1];
                y2 = (vv[2] - mu) * rstd * sb[c + 2] + sb[128 + c + 2];
                y3 = (vv[3] - mu) * rstd * sb[c + 3] + sb[128 + c + 3];
            }
            pk[i * 2]     = pk2(y0, y1);
            pk[i * 2 + 1] = pk2(y2, y3);
        }
        *(uint4*)&ldsX[trow * 132 + seg * 16] = *(uint4*)&pk[0];
        *(uint4*)&ldsX[trow * 132 + seg * 16 + 8] = *(uint4*)&pk[4];
    }
    __syncthreads();

    // ---- phase 2: qkv GEMM (M=64,N=384,K=128); wave w owns nt = 3w..3w+2 ----
    int wave = tid >> 6, lane = tid & 63, l15 = lane & 15, lg = lane >> 4;
    int mrow = lg * 4;
    bf16x8 afr[4][4];
    #pragma unroll
    for (int mt = 0; mt < 4; ++mt)
        #pragma unroll
        for (int ks = 0; ks < 4; ++ks)
            afr[mt][ks] = *(const bf16x8*)&ldsX[(mt * 16 + l15) * 132 + ks * 32 + lg * 8];
    __syncthreads();   // xln fully consumed; region becomes vT
    #pragma unroll 1
    for (int nn = 0; nn < 3; ++nn) {
        int nt = wave * 3 + nn;
        int n = nt * 16 + l15;
        const u16* wp = qkvw + n * 128 + lg * 8;
        bf16x8 bfr_[4];
        #pragma unroll
        for (int ks = 0; ks < 4; ++ks) bfr_[ks] = *(const bf16x8*)(wp + ks * 32);
        f32x4 acc[4];
        #pragma unroll
        for (int mt = 0; mt < 4; ++mt) acc[mt] = (f32x4){0.0f, 0.0f, 0.0f, 0.0f};
        #pragma unroll
        for (int ks = 0; ks < 4; ++ks)
            #pragma unroll
            for (int mt = 0; mt < 4; ++mt)
                acc[mt] = MFMA(afr[mt][ks], bfr_[ks], acc[mt]);
        float bias = sb[256 + n];
        if (n < 128) {
            #pragma unroll
            for (int mt = 0; mt < 4; ++mt)
                #pragma unroll
                for (int r = 0; r < 4; ++r)
                    ldsQK[(mt * 16 + mrow + r) * 132 + n] = bfr(acc[mt][r] + bias);
        } else if (n < 256) {
            #pragma unroll
            for (int mt = 0; mt < 4; ++mt)
                #pragma unroll
                for (int r = 0; r < 4; ++r)
                    ldsQK[8448 + (mt * 16 + mrow + r) * 132 + (n - 128)] = bfr(acc[mt][r] + bias);
        } else {
            int row = n - 256;                      // v dim index 0..127
            int sw = (row & 7) << 4;                // T2 XOR swizzle (16B granules)
            #pragma unroll
            for (int mt = 0; mt < 4; ++mt) {        // v^T: PERMUTED column slots so
                uint2 pv;                           // PV B K-order matches packed P
                pv.x = pk2(acc[mt][0] + bias, acc[mt][1] + bias);
                pv.y = pk2(acc[mt][2] + bias, acc[mt][3] + bias);
                int cb = ((mt >> 1) * 64 + mrow * 4 + (mt & 1) * 8) ^ sw;
                *(uint2*)((char*)ldsX + row * 128 + cb) = pv;
            }
        }
    }
    __syncthreads();

    // ---- phase 3: swapped attention; P stays in registers ----
    int h = wave >> 1, half = wave & 1;
    int v4 = ((wh == 31) ? 2 : 0) | ((ww == 31) ? 1 : 0);
    const float4* blp = (const float4*)bias_lane;
    bf16x8 bk[4];
    #pragma unroll
    for (int nt = 0; nt < 4; ++nt)
        bk[nt] = *(const bf16x8*)&ldsQK[8448 + (nt * 16 + l15) * 132 + h * 32 + lg * 8];
    bf16x8 aq[2];
    #pragma unroll
    for (int m2 = 0; m2 < 2; ++m2)
        aq[m2] = *(const bf16x8*)&ldsQK[((half * 2 + m2) * 16 + l15) * 132 + h * 32 + lg * 8];
    // S^T = MFMA(K, Q): D col (l15) = query, rows (lg*4+r) = key
    f32x4 sS[2][4];
    #pragma unroll
    for (int m2 = 0; m2 < 2; ++m2) {
        int mt = half * 2 + m2;
        #pragma unroll
        for (int nt = 0; nt < 4; ++nt) {
            f32x4 z = (f32x4){0.0f, 0.0f, 0.0f, 0.0f};
            z = MFMA(bk[nt], aq[m2], z);
            float4 bl = blp[((v4 * 4 + h) * 16 + mt * 4 + nt) * 64 + lane];
            sS[m2][nt][0] = z[0] * 0.2550349f + bl.x;
            sS[m2][nt][1] = z[1] * 0.2550349f + bl.y;
            sS[m2][nt][2] = z[2] * 0.2550349f + bl.z;
            sS[m2][nt][3] = z[3] * 0.2550349f + bl.w;
        }
    }
    // max-free exp2; row-sum: in-lane (16 keys) + 2 shfl_xor across lg groups
    float rinv[2];
    #pragma unroll
    for (int m2 = 0; m2 < 2; ++m2) {
        float sum = 0.0f;
        #pragma unroll
        for (int nt = 0; nt < 4; ++nt)
            #pragma unroll
            for (int r = 0; r < 4; ++r) {
                float p = exp2f(sS[m2][nt][r]);
                sS[m2][nt][r] = p;
                sum += p;
            }
        sum += __shfl_xor(sum, 16);
        sum += __shfl_xor(sum, 32);
        rinv[m2] = __builtin_amdgcn_rcpf(sum);
    }
    // PV: A-frags packed from registers (K-position e<4 -> tile 2kt, e>=4 -> 2kt+1)
    f32x4 o[2][2];
    #pragma unroll
    for (int m2 = 0; m2 < 2; ++m2)
        #pragma unroll
        for (int np = 0; np < 2; ++np) o[m2][np] = (f32x4){0.0f, 0.0f, 0.0f, 0.0f};
    #pragma unroll
    for (int kt = 0; kt < 2; ++kt) {
        bf16x8 pa[2];
        #pragma unroll
        for (int m2 = 0; m2 < 2; ++m2) {
            union { u32 w[4]; bf16x8 v; } u_;
            u_.w[0] = pk2(sS[m2][2 * kt][0], sS[m2][2 * kt][1]);
            u_.w[1] = pk2(sS[m2][2 * kt][2], sS[m2][2 * kt][3]);
            u_.w[2] = pk2(sS[m2][2 * kt + 1][0], sS[m2][2 * kt + 1][1]);
            u_.w[3] = pk2(sS[m2][2 * kt + 1][2], sS[m2][2 * kt + 1][3]);
            pa[m2] = u_.v;
        }
        #pragma unroll
        for (int np = 0; np < 2; ++np) {
            int vr = h * 32 + np * 16 + l15;
            int cb = (kt * 64 + lg * 16) ^ ((vr & 7) << 4);
            bf16x8 bv = *(const bf16x8*)((const char*)ldsX + vr * 128 + cb);
            #pragma unroll
            for (int m2 = 0; m2 < 2; ++m2)
                o[m2][np] = MFMA(pa[m2], bv, o[m2][np]);
        }
    }
    __syncthreads();   // vT reads complete before outl overwrites the region
    #pragma unroll
    for (int m2 = 0; m2 < 2; ++m2) {
        int mt = half * 2 + m2;
        #pragma unroll
        for (int np = 0; np < 2; ++np)
            #pragma unroll
            for (int r = 0; r < 4; ++r) {
                float rq = __shfl(rinv[m2], lg * 4 + r);   // rinv lives at lane l15=query
                ldsX[(mt * 16 + mrow + r) * 132 + h * 32 + np * 16 + l15] = bfr(o[m2][np][r] * rq);
            }
    }
    __syncthreads();
    u16* op = attn_out + grow * 128 + seg * 16;
    *(uint4*)op = *(const uint4*)&ldsX[trow * 132 + seg * 16];
    *(uint4*)(op + 8) = *(const uint4*)&ldsX[trow * 132 + seg * 16 + 8];
}

// ---------- fused proj + residual + LN2 + MLP (r19 verbatim — measured best 147 us) ----------
__global__ __launch_bounds__(256, 3) void swin_mlp_kernel(
    const u16* __restrict__ attn, const float* __restrict__ x,
    const u16* __restrict__ projws, const u16* __restrict__ wms,
    const float* __restrict__ projb, const float* __restrict__ g2, const float* __restrict__ b2,
    const float* __restrict__ f1b, const float* __restrict__ f2b, float* __restrict__ out)
{
    __shared__ __align__(16) u16 wbuf[2][8192];   // [8 fc1 tiles | 8 fc2 tiles] x 512
    __shared__ __align__(16) u16 sbuf[4][576];    // per-wave [16][36] (prologue only)

    int tid = threadIdx.x;
    int wave = tid >> 6, lane = tid & 63, l15 = lane & 15, lg = lane >> 4;
    long wbase = (long)blockIdx.x * 128 + wave * 32;

    // issue chunk-0 staging now (async; hides under proj + LN2)
    {
        const u16* src = wms + wave * 2048 + lane * 8;
        u16* dst = &wbuf[0][wave * 2048];
        #pragma unroll
        for (int i = 0; i < 4; ++i)
            gload16(src + i * 512, dst + i * 512);
    }

    // A-frags from attn_out (2 m-tiles)
    const u16* arow = attn + (wbase + l15) * 128 + lg * 8;
    bf16x8 aat[2][4];
    #pragma unroll
    for (int ks = 0; ks < 4; ++ks) {
        aat[0][ks] = *(const bf16x8*)(arow + ks * 32);
        aat[1][ks] = *(const bf16x8*)(arow + 2048 + ks * 32);
    }

    // proj GEMM: B-frags direct from global fragment tiles (L2-hot)
    f32x4 pacc[2][8];
    #pragma unroll
    for (int nt = 0; nt < 8; ++nt) {
        const u16* wp = projws + nt * 2048 + lane * 8;
        pacc[0][nt] = (f32x4){0.0f, 0.0f, 0.0f, 0.0f};
        pacc[1][nt] = (f32x4){0.0f, 0.0f, 0.0f, 0.0f};
        #pragma unroll
        for (int ks = 0; ks < 4; ++ks) {
            bf16x8 bw = *(const bf16x8*)(wp + ks * 512);
            pacc[0][nt] = MFMA(aat[0][ks], bw, pacc[0][nt]);
            pacc[1][nt] = MFMA(aat[1][ks], bw, pacc[1][nt]);
        }
    }

    // residual: xn = x + proj_out + projb
    #pragma unroll
    for (int nt = 0; nt < 8; ++nt) {
        float pb = projb[nt * 16 + l15];
        #pragma unroll
        for (int mt = 0; mt < 2; ++mt)
            #pragma unroll
            for (int r = 0; r < 4; ++r)
                pacc[mt][nt][r] += x[(wbase + mt * 16 + lg * 4 + r) * 128 + nt * 16 + l15] + pb;
    }
    // LN2
    float mu[2][4], rstd[2][4];
    #pragma unroll
    for (int mt = 0; mt < 2; ++mt)
        #pragma unroll
        for (int r = 0; r < 4; ++r) {
            float a = 0.0f, bq = 0.0f;
            #pragma unroll
            for (int nt = 0; nt < 8; ++nt) { a += pacc[mt][nt][r]; bq += pacc[mt][nt][r] * pacc[mt][nt][r]; }
            #pragma unroll
            for (int off = 1; off < 16; off <<= 1) { a += __shfl_xor(a, off); bq += __shfl_xor(bq, off); }
            mu[mt][r] = a * 0.0078125f;
            rstd[mt][r] = rsqrtf(bq * 0.0078125f - mu[mt][r] * mu[mt][r] + 1e-5f);
        }
    // y transpose (prologue only): 4 K-slices x 2 m-tiles via [16][36] scratch
    u16* hb = (u16*)sbuf[wave];
    bf16x8 ay[2][4];
    #pragma unroll
    for (int p = 0; p < 4; ++p) {
        #pragma unroll
        for (int mt = 0; mt < 2; ++mt) {
            #pragma unroll
            for (int n2 = 0; n2 < 2; ++n2) {
                int c = p * 32 + n2 * 16 + l15;
                float gg = g2[c], bb = b2[c];
                int nt = p * 2 + n2;
                #pragma unroll
                for (int r = 0; r < 4; ++r)
                    hb[(lg * 4 + r) * 36 + n2 * 16 + l15] =
                        bfr((pacc[mt][nt][r] - mu[mt][r]) * rstd[mt][r] * gg + bb);
            }
            __builtin_amdgcn_sched_barrier(0);
            ay[mt][p] = *(const bf16x8*)&hb[l15 * 36 + lg * 8];
            __builtin_amdgcn_sched_barrier(0);
        }
    }
    // fold fc2 bias: pacc = xn + f2b; chunk-loop MFMAs accumulate on top
    #pragma unroll
    for (int nt = 0; nt < 8; ++nt) {
        float fb = f2b[nt * 16 + l15];
        #pragma unroll
        for (int mt = 0; mt < 2; ++mt)
            #pragma unroll
            for (int r = 0; r < 4; ++r)
                pacc[mt][nt][r] += fb;
    }
    __syncthreads();   // chunk 0 staged (vmcnt drained) & visible

    #pragma unroll 1
    for (int cc = 0; cc < 16; ++cc) {
        int cur = cc & 1;
        // prefetch chunk cc+1 (async; buf[cur^1] fully consumed before last barrier)
        if (cc < 15) {
            const u16* src = wms + (cc + 1) * 8192 + wave * 2048 + lane * 8;
            u16* dst = &wbuf[cur ^ 1][wave * 2048];
            #pragma unroll
            for (int i = 0; i < 4; ++i)
                gload16(src + i * 512, dst + i * 512);
        }
        // fc1 as h^T = MFMA(W1-frag, y-frag): D lane l15 = token, rows = hid
        f32x4 h[2][2];
        h[0][0] = h[0][1] = h[1][0] = h[1][1] = (f32x4){0.0f, 0.0f, 0.0f, 0.0f};
        #pragma unroll
        for (int mh = 0; mh < 2; ++mh)
            #pragma unroll
            for (int ks = 0; ks < 4; ++ks) {
                bf16x8 w1 = *(const bf16x8*)&wbuf[cur][(mh * 4 + ks) * 512 + lane * 8];
                h[0][mh] = MFMA(w1, ay[0][ks], h[0][mh]);
                h[1][mh] = MFMA(w1, ay[1][ks], h[1][mh]);
            }
        // GELU in registers; pack fc2 A-frags (lane holds hids {lg*4+r, 16+lg*4+r})
        float4 fb0 = *(const float4*)(f1b + cc * 32 + lg * 4);
        float4 fb1 = *(const float4*)(f1b + cc * 32 + 16 + lg * 4);
        float b0[4] = {fb0.x, fb0.y, fb0.z, fb0.w};
        float b1[4] = {fb1.x, fb1.y, fb1.z, fb1.w};
        bf16x8 ah[2];
        #pragma unroll
        for (int mt = 0; mt < 2; ++mt) {
            float g0[4], g1[4];
            #pragma unroll
            for (int r = 0; r < 4; ++r) {
                g0[r] = gelu_poly(h[mt][0][r] + b0[r]);
                g1[r] = gelu_poly(h[mt][1][r] + b1[r]);
            }
            union { u32 w[4]; bf16x8 v; } u_;
            u_.w[0] = pk2(g0[0], g0[1]);
            u_.w[1] = pk2(g0[2], g0[3]);
            u_.w[2] = pk2(g1[0], g1[1]);
            u_.w[3] = pk2(g1[2], g1[3]);
            ah[mt] = u_.v;
        }
        // fc2 (K=32, permuted): 16 MFMAs accumulating into pacc
        #pragma unroll
        for (int nt = 0; nt < 8; ++nt) {
            bf16x8 bw = *(const bf16x8*)&wbuf[cur][(8 + nt) * 512 + lane * 8];
            pacc[0][nt] = MFMA(ah[0], bw, pacc[0][nt]);
            pacc[1][nt] = MFMA(ah[1], bw, pacc[1][nt]);
        }
        __syncthreads();   // chunk cc+1 staged & all waves done with buf[cur]
    }
    // epilogue: pacc = xn + f2b + fc2_out
    #pragma unroll
    for (int nt = 0; nt < 8; ++nt)
        #pragma unroll
        for (int mt = 0; mt < 2; ++mt)
            #pragma unroll
            for (int r = 0; r < 4; ++r)
                out[(wbase + mt * 16 + lg * 4 + r) * 128 + nt * 16 + l15] = pacc[mt][nt][r];
}

extern "C" void kernel_launch(void* const* d_in, const int* in_sizes, int n_in,
                              void* d_out, int out_size, void* d_ws, size_t ws_size,
                              hipStream_t stream)
{
    const float* x     = (const float*)d_in[0];
    const float* n1g   = (const float*)d_in[1];
    const float* n1b   = (const float*)d_in[2];
    const float* qkvw  = (const float*)d_in[3];
    const float* qkvb  = (const float*)d_in[4];
    const float* rpb   = (const float*)d_in[5];
    const float* projw = (const float*)d_in[6];
    const float* projb = (const float*)d_in[7];
    const float* n2g   = (const float*)d_in[8];
    const float* n2b   = (const float*)d_in[9];
    const float* f1w   = (const float*)d_in[10];
    const float* f1b   = (const float*)d_in[11];
    const float* f2w   = (const float*)d_in[12];
    const float* f2b   = (const float*)d_in[13];

    char* ws = (char*)d_ws;
    u16* attn_buf = (u16*)ws;                                  // 67,108,864 B
    u16* wb = (u16*)(ws + 67108864);                           // 212992 u16 = 425,984 B
    float* bias_lane = (float*)(ws + 67108864 + 425984);       // 262,144 B
    u16* qkvwb  = wb;                                          // [0,49152)
    u16* projws = wb + 49152;                                  // [49152,81920)
    u16* wms    = wb + 81920;                                  // [81920,212992)

    swin_prep_kernel<<<1088, 256, 0, stream>>>(qkvw, projw, f1w, f2w, rpb, wb, bias_lane);
    swin_attn_kernel<<<4096, 512, 0, stream>>>(x, n1g, n1b, qkvb, qkvwb, bias_lane, attn_buf);
    swin_mlp_kernel<<<2048, 256, 0, stream>>>(attn_buf, x, projws, wms,
                                              projb, n2g, n2b, f1b, f2b, (float*)d_out);
}

// Round 21
// 224.001 us; speedup vs baseline: 1.1077x; 1.0296x over previous
//
#include <hip/hip_runtime.h>
#include <hip/hip_bf16.h>

typedef unsigned short u16;
typedef unsigned int u32;
typedef __attribute__((ext_vector_type(8))) short bf16x8;
typedef __attribute__((ext_vector_type(4))) float f32x4;

__device__ __forceinline__ u32 fbits(float f) { union { float f; u32 u; } a; a.f = f; return a.u; }
__device__ __forceinline__ u16 f2bf(float f) {   // RNE (prep only, cold)
    u32 u = fbits(f);
    return (u16)((u + 0x7FFFu + ((u >> 16) & 1u)) >> 16);
}
// hot-path round-half-up conversions
__device__ __forceinline__ u16 bfr(float f) { return (u16)((fbits(f) + 0x8000u) >> 16); }
__device__ __forceinline__ u32 pk2(float lo, float hi) {
    return __builtin_amdgcn_perm(fbits(hi) + 0x8000u, fbits(lo) + 0x8000u, 0x07060302u);
}
__device__ __forceinline__ float bf2f(u16 b) {
    union { u32 u; float f; } a; a.u = ((u32)b) << 16; return a.f;
}
// transcendental-free GELU: t*sigma(1.702t), odd quintic, clamp +-3.
__device__ __forceinline__ float gelu_poly(float t) {
    float u = fminf(3.0f, fmaxf(-3.0f, t));
    float u2 = u * u;
    float w = fmaf(u2, 0.00319581f, -0.0550159f);
    w = fmaf(u2, w, 0.401174f);
    float sg = fmaf(u, w, 0.5f);
    return t * sg;
}

#define MFMA(a, b, c) __builtin_amdgcn_mfma_f32_16x16x32_bf16(a, b, c, 0, 0, 0)

// async global->LDS, 16B per lane; dst must be wave-uniform (HW adds lane*16)
__device__ __forceinline__ void gload16(const u16* g, u16* l) {
    __builtin_amdgcn_global_load_lds(
        (const __attribute__((address_space(1))) void*)g,
        (__attribute__((address_space(3))) void*)l, 16, 0, 0);
}

// ---------- prep (r20 verbatim) ----------
__global__ void swin_prep_kernel(const float* __restrict__ qkv_w, const float* __restrict__ proj_w,
                                 const float* __restrict__ fc1_w, const float* __restrict__ fc2_w,
                                 const float* __restrict__ rpb, u16* __restrict__ wout,
                                 float* __restrict__ bias_lane)
{
    int idx = blockIdx.x * 256 + threadIdx.x;
    if (idx < 49152) wout[idx] = f2bf(qkv_w[idx]);
    else if (idx < 81920) {
        int j = idx - 49152;
        int tile = j >> 9, lane = (j >> 3) & 63, e = j & 7;
        int nt = tile >> 2, ks = tile & 3;
        wout[idx] = f2bf(proj_w[(nt * 16 + (lane & 15)) * 128 + ks * 32 + (lane >> 4) * 8 + e]);
    } else if (idx < 212992) {
        int j = idx - 81920;
        int chunk = j >> 13, rest = j & 8191;
        int tile = rest >> 9, lane = (rest >> 3) & 63, e = rest & 7;
        int lg = lane >> 4;
        float v;
        if (tile < 8) {
            int mh = tile >> 2, ks = tile & 3;
            v = fc1_w[(chunk * 32 + mh * 16 + (lane & 15)) * 128 + ks * 32 + lg * 8 + e];
        } else {
            int nt = tile - 8;
            int hid = (e < 4) ? (lg * 4 + e) : (16 + lg * 4 + (e - 4));
            v = fc2_w[(nt * 16 + (lane & 15)) * 512 + chunk * 32 + hid];
        }
        wout[idx] = f2bf(v);
    } else {
        int t = idx - 212992;  // < 65536
        int r = t & 3, lane = (t >> 2) & 63, nt = (t >> 8) & 3, mt = (t >> 10) & 3;
        int h = (t >> 12) & 3, v = (t >> 14) & 3;
        int i = mt * 16 + (lane & 15);              // query (D col after swap)
        int j = nt * 16 + ((lane >> 4) << 2) + r;   // key (D row after swap)
        int ri = i >> 3, ci = i & 7, rj = j >> 3, cj = j & 7;
        int rpi = (ri - rj + 7) * 15 + (ci - cj + 7);
        float bv = rpb[rpi * 4 + h];
        int vh = v >> 1, vw = v & 1;
        int regi = (vh ? (ri < 4 ? 1 : 2) : 0) * 3 + (vw ? (ci < 4 ? 1 : 2) : 0);
        int regj = (vh ? (rj < 4 ? 1 : 2) : 0) * 3 + (vw ? (cj < 4 ? 1 : 2) : 0);
        if (regi != regj) bv -= 100.0f;
        bias_lane[t] = bv * 1.4426950408889634f;   // pre-scale by 1/ln2 for exp2
    }
}

// ---------- fused LN1 + qkv + windowed attention (r20 verbatim) ----------
__global__ __launch_bounds__(512, 4) void swin_attn_kernel(
    const float* __restrict__ x, const float* __restrict__ g1, const float* __restrict__ b1,
    const float* __restrict__ qkvb, const u16* __restrict__ qkvw,
    const float* __restrict__ bias_lane, u16* __restrict__ attn_out)
{
    __shared__ __align__(16) u16 ldsX[8448];     // xln[64][132] | vT swz | outl[64][132]
    __shared__ __align__(16) u16 ldsQK[16896];   // q[64][132] | k[64][132]
    __shared__ float sb[640];                    // g1 | b1 | qkv_b

    int tid = threadIdx.x;
    int wid = blockIdx.x;
    int bb_ = wid >> 10, wh = (wid >> 5) & 31, ww = wid & 31;

    for (int i = tid; i < 640; i += 512) {
        float v;
        if (i < 128) v = g1[i];
        else if (i < 256) v = b1[i - 128];
        else v = qkvb[i - 256];
        sb[i] = v;
    }

    // ---- phase 1: gather rolled x rows, LN1 -> xln ----
    int trow = tid >> 3, seg = tid & 7;
    int rn = trow >> 3, cn = trow & 7;
    int srow = (wh * 8 + rn + 4) & 255;
    int scol = (ww * 8 + cn + 4) & 255;
    long grow = (long)bb_ * 65536 + srow * 256 + scol;
    const float4* xrow = (const float4*)(x + grow * 128 + seg * 16);
    float4 xv[4];
    #pragma unroll
    for (int i = 0; i < 4; ++i) xv[i] = xrow[i];
    __syncthreads();  // sb visible

    float s1 = 0.0f, s2 = 0.0f;
    #pragma unroll
    for (int i = 0; i < 4; ++i) {
        float4 v = xv[i];
        s1 += v.x + v.y + v.z + v.w;
        s2 += v.x * v.x + v.y * v.y + v.z * v.z + v.w * v.w;
    }
    #pragma unroll
    for (int off = 1; off < 8; off <<= 1) { s1 += __shfl_xor(s1, off); s2 += __shfl_xor(s2, off); }
    float mu = s1 * 0.0078125f;
    float rstd = rsqrtf(s2 * 0.0078125f - mu * mu + 1e-5f);
    {
        u32 pk[8];
        #pragma unroll
        for (int i = 0; i < 4; ++i) {
            float vv[4] = {xv[i].x, xv[i].y, xv[i].z, xv[i].w};
            float y0, y1, y2, y3;
            {
                int c = seg * 16 + i * 4;
                y0 = (vv[0] - mu) * rstd * sb[c + 0] + sb[128 + c + 0];
                y1 = (vv[1] - mu) * rstd * sb[c + 1] + sb[128 + c + 1];
                y2 = (vv[2] - mu) * rstd * sb[c + 2] + sb[128 + c + 2];
                y3 = (vv[3] - mu) * rstd * sb[c + 3] + sb[128 + c + 3];
            }
            pk[i * 2]     = pk2(y0, y1);
            pk[i * 2 + 1] = pk2(y2, y3);
        }
        *(uint4*)&ldsX[trow * 132 + seg * 16] = *(uint4*)&pk[0];
        *(uint4*)&ldsX[trow * 132 + seg * 16 + 8] = *(uint4*)&pk[4];
    }
    __syncthreads();

    // ---- phase 2: qkv GEMM (M=64,N=384,K=128); wave w owns nt = 3w..3w+2 ----
    int wave = tid >> 6, lane = tid & 63, l15 = lane & 15, lg = lane >> 4;
    int mrow = lg * 4;
    bf16x8 afr[4][4];
    #pragma unroll
    for (int mt = 0; mt < 4; ++mt)
        #pragma unroll
        for (int ks = 0; ks < 4; ++ks)
            afr[mt][ks] = *(const bf16x8*)&ldsX[(mt * 16 + l15) * 132 + ks * 32 + lg * 8];
    __syncthreads();   // xln fully consumed; region becomes vT
    #pragma unroll 1
    for (int nn = 0; nn < 3; ++nn) {
        int nt = wave * 3 + nn;
        int n = nt * 16 + l15;
        const u16* wp = qkvw + n * 128 + lg * 8;
        bf16x8 bfr_[4];
        #pragma unroll
        for (int ks = 0; ks < 4; ++ks) bfr_[ks] = *(const bf16x8*)(wp + ks * 32);
        f32x4 acc[4];
        #pragma unroll
        for (int mt = 0; mt < 4; ++mt) acc[mt] = (f32x4){0.0f, 0.0f, 0.0f, 0.0f};
        #pragma unroll
        for (int ks = 0; ks < 4; ++ks)
            #pragma unroll
            for (int mt = 0; mt < 4; ++mt)
                acc[mt] = MFMA(afr[mt][ks], bfr_[ks], acc[mt]);
        float bias = sb[256 + n];
        if (n < 128) {
            #pragma unroll
            for (int mt = 0; mt < 4; ++mt)
                #pragma unroll
                for (int r = 0; r < 4; ++r)
                    ldsQK[(mt * 16 + mrow + r) * 132 + n] = bfr(acc[mt][r] + bias);
        } else if (n < 256) {
            #pragma unroll
            for (int mt = 0; mt < 4; ++mt)
                #pragma unroll
                for (int r = 0; r < 4; ++r)
                    ldsQK[8448 + (mt * 16 + mrow + r) * 132 + (n - 128)] = bfr(acc[mt][r] + bias);
        } else {
            int row = n - 256;                      // v dim index 0..127
            int sw = (row & 7) << 4;                // T2 XOR swizzle (16B granules)
            #pragma unroll
            for (int mt = 0; mt < 4; ++mt) {        // v^T: PERMUTED column slots so
                uint2 pv;                           // PV B K-order matches packed P
                pv.x = pk2(acc[mt][0] + bias, acc[mt][1] + bias);
                pv.y = pk2(acc[mt][2] + bias, acc[mt][3] + bias);
                int cb = ((mt >> 1) * 64 + mrow * 4 + (mt & 1) * 8) ^ sw;
                *(uint2*)((char*)ldsX + row * 128 + cb) = pv;
            }
        }
    }
    __syncthreads();

    // ---- phase 3: swapped attention; P stays in registers ----
    int h = wave >> 1, half = wave & 1;
    int v4 = ((wh == 31) ? 2 : 0) | ((ww == 31) ? 1 : 0);
    const float4* blp = (const float4*)bias_lane;
    bf16x8 bk[4];
    #pragma unroll
    for (int nt = 0; nt < 4; ++nt)
        bk[nt] = *(const bf16x8*)&ldsQK[8448 + (nt * 16 + l15) * 132 + h * 32 + lg * 8];
    bf16x8 aq[2];
    #pragma unroll
    for (int m2 = 0; m2 < 2; ++m2)
        aq[m2] = *(const bf16x8*)&ldsQK[((half * 2 + m2) * 16 + l15) * 132 + h * 32 + lg * 8];
    // S^T = MFMA(K, Q): D col (l15) = query, rows (lg*4+r) = key
    f32x4 sS[2][4];
    #pragma unroll
    for (int m2 = 0; m2 < 2; ++m2) {
        int mt = half * 2 + m2;
        #pragma unroll
        for (int nt = 0; nt < 4; ++nt) {
            f32x4 z = (f32x4){0.0f, 0.0f, 0.0f, 0.0f};
            z = MFMA(bk[nt], aq[m2], z);
            float4 bl = blp[((v4 * 4 + h) * 16 + mt * 4 + nt) * 64 + lane];
            sS[m2][nt][0] = z[0] * 0.2550349f + bl.x;
            sS[m2][nt][1] = z[1] * 0.2550349f + bl.y;
            sS[m2][nt][2] = z[2] * 0.2550349f + bl.z;
            sS[m2][nt][3] = z[3] * 0.2550349f + bl.w;
        }
    }
    // max-free exp2; row-sum: in-lane (16 keys) + 2 shfl_xor across lg groups
    float rinv[2];
    #pragma unroll
    for (int m2 = 0; m2 < 2; ++m2) {
        float sum = 0.0f;
        #pragma unroll
        for (int nt = 0; nt < 4; ++nt)
            #pragma unroll
            for (int r = 0; r < 4; ++r) {
                float p = exp2f(sS[m2][nt][r]);
                sS[m2][nt][r] = p;
                sum += p;
            }
        sum += __shfl_xor(sum, 16);
        sum += __shfl_xor(sum, 32);
        rinv[m2] = __builtin_amdgcn_rcpf(sum);
    }
    // PV: A-frags packed from registers (K-position e<4 -> tile 2kt, e>=4 -> 2kt+1)
    f32x4 o[2][2];
    #pragma unroll
    for (int m2 = 0; m2 < 2; ++m2)
        #pragma unroll
        for (int np = 0; np < 2; ++np) o[m2][np] = (f32x4){0.0f, 0.0f, 0.0f, 0.0f};
    #pragma unroll
    for (int kt = 0; kt < 2; ++kt) {
        bf16x8 pa[2];
        #pragma unroll
        for (int m2 = 0; m2 < 2; ++m2) {
            union { u32 w[4]; bf16x8 v; } u_;
            u_.w[0] = pk2(sS[m2][2 * kt][0], sS[m2][2 * kt][1]);
            u_.w[1] = pk2(sS[m2][2 * kt][2], sS[m2][2 * kt][3]);
            u_.w[2] = pk2(sS[m2][2 * kt + 1][0], sS[m2][2 * kt + 1][1]);
            u_.w[3] = pk2(sS[m2][2 * kt + 1][2], sS[m2][2 * kt + 1][3]);
            pa[m2] = u_.v;
        }
        #pragma unroll
        for (int np = 0; np < 2; ++np) {
            int vr = h * 32 + np * 16 + l15;
            int cb = (kt * 64 + lg * 16) ^ ((vr & 7) << 4);
            bf16x8 bv = *(const bf16x8*)((const char*)ldsX + vr * 128 + cb);
            #pragma unroll
            for (int m2 = 0; m2 < 2; ++m2)
                o[m2][np] = MFMA(pa[m2], bv, o[m2][np]);
        }
    }
    __syncthreads();   // vT reads complete before outl overwrites the region
    #pragma unroll
    for (int m2 = 0; m2 < 2; ++m2) {
        int mt = half * 2 + m2;
        #pragma unroll
        for (int np = 0; np < 2; ++np)
            #pragma unroll
            for (int r = 0; r < 4; ++r) {
                float rq = __shfl(rinv[m2], lg * 4 + r);   // rinv lives at lane l15=query
                ldsX[(mt * 16 + mrow + r) * 132 + h * 32 + np * 16 + l15] = bfr(o[m2][np][r] * rq);
            }
    }
    __syncthreads();
    u16* op = attn_out + grow * 128 + seg * 16;
    *(uint4*)op = *(const uint4*)&ldsX[trow * 132 + seg * 16];
    *(uint4*)(op + 8) = *(const uint4*)&ldsX[trow * 132 + seg * 16 + 8];
}

// ---------- fused proj + residual + LN2 + MLP (r19 + T4 counted-vmcnt pipeline) ----------
// Triple-buffered weight staging: gl(cc+2) issued at top of chunk cc; end-of-chunk
// uses s_waitcnt vmcnt(4) (4 newest outstanding = gl(cc+2); in-order retirement
// guarantees gl(cc+1) landed) + raw s_barrier + sched_barrier(0). Loop is vmcnt-
// clean: f1b served from LDS (lgkm). y-transpose scratch lives in wbuf[2] (idle
// during prologue: first gl into it is chunk 2, issued in chunk 0's body).
__global__ __launch_bounds__(256, 3) void swin_mlp_kernel(
    const u16* __restrict__ attn, const float* __restrict__ x,
    const u16* __restrict__ projws, const u16* __restrict__ wms,
    const float* __restrict__ projb, const float* __restrict__ g2, const float* __restrict__ b2,
    const float* __restrict__ f1b, const float* __restrict__ f2b, float* __restrict__ out)
{
    __shared__ __align__(16) u16 wbuf[3][8192];   // 49152 B triple buffer
    __shared__ __align__(16) float f1s[512];      // 2048 B fc1 bias (lgkm path)

    int tid = threadIdx.x;
    int wave = tid >> 6, lane = tid & 63, l15 = lane & 15, lg = lane >> 4;
    long wbase = (long)blockIdx.x * 128 + wave * 32;

    // issue chunk-0 and chunk-1 staging now (async; hide under proj + LN2)
    {
        const u16* src = wms + wave * 2048 + lane * 8;
        #pragma unroll
        for (int i = 0; i < 4; ++i)
            gload16(src + i * 512, &wbuf[0][wave * 2048] + i * 512);
        #pragma unroll
        for (int i = 0; i < 4; ++i)
            gload16(src + 8192 + i * 512, &wbuf[1][wave * 2048] + i * 512);
    }
    // f1b -> LDS so the chunk loop has no vmcnt traffic besides prefetch
    f1s[tid] = f1b[tid];
    f1s[tid + 256] = f1b[tid + 256];

    // A-frags from attn_out (2 m-tiles)
    const u16* arow = attn + (wbase + l15) * 128 + lg * 8;
    bf16x8 aat[2][4];
    #pragma unroll
    for (int ks = 0; ks < 4; ++ks) {
        aat[0][ks] = *(const bf16x8*)(arow + ks * 32);
        aat[1][ks] = *(const bf16x8*)(arow + 2048 + ks * 32);
    }

    // proj GEMM: B-frags direct from global fragment tiles (L2-hot)
    f32x4 pacc[2][8];
    #pragma unroll
    for (int nt = 0; nt < 8; ++nt) {
        const u16* wp = projws + nt * 2048 + lane * 8;
        pacc[0][nt] = (f32x4){0.0f, 0.0f, 0.0f, 0.0f};
        pacc[1][nt] = (f32x4){0.0f, 0.0f, 0.0f, 0.0f};
        #pragma unroll
        for (int ks = 0; ks < 4; ++ks) {
            bf16x8 bw = *(const bf16x8*)(wp + ks * 512);
            pacc[0][nt] = MFMA(aat[0][ks], bw, pacc[0][nt]);
            pacc[1][nt] = MFMA(aat[1][ks], bw, pacc[1][nt]);
        }
    }

    // residual: xn = x + proj_out + projb
    #pragma unroll
    for (int nt = 0; nt < 8; ++nt) {
        float pb = projb[nt * 16 + l15];
        #pragma unroll
        for (int mt = 0; mt < 2; ++mt)
            #pragma unroll
            for (int r = 0; r < 4; ++r)
                pacc[mt][nt][r] += x[(wbase + mt * 16 + lg * 4 + r) * 128 + nt * 16 + l15] + pb;
    }
    // LN2
    float mu[2][4], rstd[2][4];
    #pragma unroll
    for (int mt = 0; mt < 2; ++mt)
        #pragma unroll
        for (int r = 0; r < 4; ++r) {
            float a = 0.0f, bq = 0.0f;
            #pragma unroll
            for (int nt = 0; nt < 8; ++nt) { a += pacc[mt][nt][r]; bq += pacc[mt][nt][r] * pacc[mt][nt][r]; }
            #pragma unroll
            for (int off = 1; off < 16; off <<= 1) { a += __shfl_xor(a, off); bq += __shfl_xor(bq, off); }
            mu[mt][r] = a * 0.0078125f;
            rstd[mt][r] = rsqrtf(bq * 0.0078125f - mu[mt][r] * mu[mt][r] + 1e-5f);
        }
    // y transpose (prologue only): scratch = wbuf[2] quadrant (idle until chunk 2)
    u16* hb = &wbuf[2][wave * 2048];
    bf16x8 ay[2][4];
    #pragma unroll
    for (int p = 0; p < 4; ++p) {
        #pragma unroll
        for (int mt = 0; mt < 2; ++mt) {
            #pragma unroll
            for (int n2 = 0; n2 < 2; ++n2) {
                int c = p * 32 + n2 * 16 + l15;
                float gg = g2[c], bb = b2[c];
                int nt = p * 2 + n2;
                #pragma unroll
                for (int r = 0; r < 4; ++r)
                    hb[(lg * 4 + r) * 36 + n2 * 16 + l15] =
                        bfr((pacc[mt][nt][r] - mu[mt][r]) * rstd[mt][r] * gg + bb);
            }
            __builtin_amdgcn_sched_barrier(0);
            ay[mt][p] = *(const bf16x8*)&hb[l15 * 36 + lg * 8];
            __builtin_amdgcn_sched_barrier(0);
        }
    }
    // fold fc2 bias: pacc = xn + f2b; chunk-loop MFMAs accumulate on top
    #pragma unroll
    for (int nt = 0; nt < 8; ++nt) {
        float fb = f2b[nt * 16 + l15];
        #pragma unroll
        for (int mt = 0; mt < 2; ++mt)
            #pragma unroll
            for (int r = 0; r < 4; ++r)
                pacc[mt][nt][r] += fb;
    }
    // chunk 0 must be resident (chunk 1 may stay in flight: 4 newest)
    asm volatile("s_waitcnt vmcnt(4)" ::: "memory");
    __builtin_amdgcn_s_barrier();
    __builtin_amdgcn_sched_barrier(0);

    int cur = 0, pre = 2;
    #pragma unroll 1
    for (int cc = 0; cc < 16; ++cc) {
        // prefetch chunk cc+2 into the buffer freed at the end of chunk cc-1
        if (cc < 14) {
            const u16* src = wms + (cc + 2) * 8192 + wave * 2048 + lane * 8;
            u16* dst = &wbuf[pre][wave * 2048];
            #pragma unroll
            for (int i = 0; i < 4; ++i)
                gload16(src + i * 512, dst + i * 512);
        }
        const u16* wc = &wbuf[cur][0];
        // fc1 as h^T = MFMA(W1-frag, y-frag): D lane l15 = token, rows = hid
        f32x4 h[2][2];
        h[0][0] = h[0][1] = h[1][0] = h[1][1] = (f32x4){0.0f, 0.0f, 0.0f, 0.0f};
        #pragma unroll
        for (int mh = 0; mh < 2; ++mh)
            #pragma unroll
            for (int ks = 0; ks < 4; ++ks) {
                bf16x8 w1 = *(const bf16x8*)(wc + (mh * 4 + ks) * 512 + lane * 8);
                h[0][mh] = MFMA(w1, ay[0][ks], h[0][mh]);
                h[1][mh] = MFMA(w1, ay[1][ks], h[1][mh]);
            }
        // GELU in registers; fc2 A-frags packed from D regs; f1b via LDS (lgkm)
        float4 fb0 = *(const float4*)&f1s[cc * 32 + lg * 4];
        float4 fb1 = *(const float4*)&f1s[cc * 32 + 16 + lg * 4];
        float b0[4] = {fb0.x, fb0.y, fb0.z, fb0.w};
        float b1[4] = {fb1.x, fb1.y, fb1.z, fb1.w};
        bf16x8 ah[2];
        #pragma unroll
        for (int mt = 0; mt < 2; ++mt) {
            float g0[4], g1[4];
            #pragma unroll
            for (int r = 0; r < 4; ++r) {
                g0[r] = gelu_poly(h[mt][0][r] + b0[r]);
                g1[r] = gelu_poly(h[mt][1][r] + b1[r]);
            }
            union { u32 w[4]; bf16x8 v; } u_;
            u_.w[0] = pk2(g0[0], g0[1]);
            u_.w[1] = pk2(g0[2], g0[3]);
            u_.w[2] = pk2(g1[0], g1[1]);
            u_.w[3] = pk2(g1[2], g1[3]);
            ah[mt] = u_.v;
        }
        // fc2 (K=32, permuted): 16 MFMAs accumulating into pacc
        #pragma unroll
        for (int nt = 0; nt < 8; ++nt) {
            bf16x8 bw = *(const bf16x8*)(wc + (8 + nt) * 512 + lane * 8);
            pacc[0][nt] = MFMA(ah[0], bw, pacc[0][nt]);
            pacc[1][nt] = MFMA(ah[1], bw, pacc[1][nt]);
        }
        // counted-vmcnt barrier: gl(cc+1) must be resident; gl(cc+2) stays in flight
        if (cc < 15) {
            if (cc < 14) asm volatile("s_waitcnt vmcnt(4)" ::: "memory");
            else         asm volatile("s_waitcnt vmcnt(0)" ::: "memory");
            __builtin_amdgcn_s_barrier();
            __builtin_amdgcn_sched_barrier(0);
        }
        cur = (cur == 2) ? 0 : cur + 1;
        pre = (pre == 2) ? 0 : pre + 1;
    }
    // epilogue: pacc = xn + f2b + fc2_out
    #pragma unroll
    for (int nt = 0; nt < 8; ++nt)
        #pragma unroll
        for (int mt = 0; mt < 2; ++mt)
            #pragma unroll
            for (int r = 0; r < 4; ++r)
                out[(wbase + mt * 16 + lg * 4 + r) * 128 + nt * 16 + l15] = pacc[mt][nt][r];
}

extern "C" void kernel_launch(void* const* d_in, const int* in_sizes, int n_in,
                              void* d_out, int out_size, void* d_ws, size_t ws_size,
                              hipStream_t stream)
{
    const float* x     = (const float*)d_in[0];
    const float* n1g   = (const float*)d_in[1];
    const float* n1b   = (const float*)d_in[2];
    const float* qkvw  = (const float*)d_in[3];
    const float* qkvb  = (const float*)d_in[4];
    const float* rpb   = (const float*)d_in[5];
    const float* projw = (const float*)d_in[6];
    const float* projb = (const float*)d_in[7];
    const float* n2g   = (const float*)d_in[8];
    const float* n2b   = (const float*)d_in[9];
    const float* f1w   = (const float*)d_in[10];
    const float* f1b   = (const float*)d_in[11];
    const float* f2w   = (const float*)d_in[12];
    const float* f2b   = (const float*)d_in[13];

    char* ws = (char*)d_ws;
    u16* attn_buf = (u16*)ws;                                  // 67,108,864 B
    u16* wb = (u16*)(ws + 67108864);                           // 212992 u16 = 425,984 B
    float* bias_lane = (float*)(ws + 67108864 + 425984);       // 262,144 B
    u16* qkvwb  = wb;                                          // [0,49152)
    u16* projws = wb + 49152;                                  // [49152,81920)
    u16* wms    = wb + 81920;                                  // [81920,212992)

    swin_prep_kernel<<<1088, 256, 0, stream>>>(qkvw, projw, f1w, f2w, rpb, wb, bias_lane);
    swin_attn_kernel<<<4096, 512, 0, stream>>>(x, n1g, n1b, qkvb, qkvwb, bias_lane, attn_buf);
    swin_mlp_kernel<<<2048, 256, 0, stream>>>(attn_buf, x, projws, wms,
                                              projb, n2g, n2b, f1b, f2b, (float*)d_out);
}